// Round 4
// baseline (1267.794 us; speedup 1.0000x reference)
//
#include <hip/hip_runtime.h>
#include <hip/hip_bf16.h>
#include <cstdint>

// ---------------------------------------------------------------------------
// GAT 2-layer model on MI355X.
// R3: aggregation restructured as edge-parallel SpMM.
//   Old wave-per-node design was latency-duty-cycle bound (~0.6-0.9 TB/s
//   effective gather: serial softmax phases drained the memory pipe between
//   gather bursts). New design:
//     coef_kernel: per-node softmax -> per-edge coef (no gathers, cheap)
//     spmm_kernel: edge-parallel; LDS-staged (src,dst,coef); 16-lane groups
//       walk 32 contiguous edges in packs of 4 -> 4 row-loads always in
//       flight; dst-sorted => register accumulate, atomicAdd flush only on
//       dst change (~5M f32 atomics/layer).
//     post_kernel: bias+ELU (+ fused mean-pool atomics for layer 2).
// ---------------------------------------------------------------------------

__device__ __forceinline__ float wave_reduce_sum(float v) {
#pragma unroll
  for (int off = 32; off > 0; off >>= 1) v += __shfl_xor(v, off, 64);
  return v;
}

// ---------------- CSR build ----------------

__global__ void deg_kernel(const int* __restrict__ ei, int E, int N,
                           int* __restrict__ deg) {
  int t = blockIdx.x * blockDim.x + threadIdx.x;
  int total = E + N;
  if (t >= total) return;
  int d = (t < E) ? ei[E + t] : (t - E);  // self loops appended
  atomicAdd(&deg[d], 1);
}

__global__ void scan1_kernel(const int* __restrict__ deg, int* __restrict__ rowptr,
                             int* __restrict__ partials, int n) {
  __shared__ int wsum[4];
  int t = threadIdx.x;
  int lane = t & 63, wv = t >> 6;
  int base = blockIdx.x * 2048 + t * 8;
  int v[8];
  int s = 0;
#pragma unroll
  for (int i = 0; i < 8; i++) {
    int idx = base + i;
    v[i] = (idx < n) ? deg[idx] : 0;
    s += v[i];
  }
  int x = s;
#pragma unroll
  for (int off = 1; off < 64; off <<= 1) {
    int u = __shfl_up(x, off, 64);
    if (lane >= off) x += u;
  }
  if (lane == 63) wsum[wv] = x;
  __syncthreads();
  int woff = 0;
  for (int j = 0; j < wv; j++) woff += wsum[j];
  int excl = woff + x - s;
#pragma unroll
  for (int i = 0; i < 8; i++) {
    int idx = base + i;
    if (idx < n) rowptr[idx] = excl;
    excl += v[i];
  }
  if (t == 255) partials[blockIdx.x] = woff + x;
}

__global__ void scan2_kernel(int* __restrict__ partials, int nb,
                             int* __restrict__ rowptr_end) {
  if (threadIdx.x == 0 && blockIdx.x == 0) {
    int run = 0;
    for (int i = 0; i < nb; i++) {
      int t = partials[i];
      partials[i] = run;
      run += t;
    }
    *rowptr_end = run;
  }
}

__global__ void scan3_kernel(int* __restrict__ rowptr, const int* __restrict__ partials,
                             int n) {
  int idx = blockIdx.x * blockDim.x + threadIdx.x;
  if (idx < n) rowptr[idx] += partials[idx >> 11];
}

__global__ void scatter_kernel(const int* __restrict__ ei, int E, int N,
                               int* __restrict__ cursor, int* __restrict__ csrc,
                               int* __restrict__ cdst) {
  int t = blockIdx.x * blockDim.x + threadIdx.x;
  int total = E + N;
  if (t >= total) return;
  int s, d;
  if (t < E) {
    s = ei[t];
    d = ei[E + t];
  } else {
    s = d = t - E;
  }
  int pos = atomicAdd(&cursor[d], 1);
  csrc[pos] = s;
  cdst[pos] = d;
}

// ---------------- dense compute ----------------

// C[N][64] = A[N][KDIM] @ W[KDIM][64], fp32, 64x64 tile, 4x4 microtile
template <int KDIM>
__global__ __launch_bounds__(256) void gemm64(const float* __restrict__ A,
                                              const float* __restrict__ W,
                                              float* __restrict__ C, int N) {
  __shared__ float As[32][68];
  __shared__ float Ws[32][68];
  const int block_m = blockIdx.x * 64;
  const int t = threadIdx.x;
  const int tc = t & 15;
  const int tr = t >> 4;
  const int c0 = tc * 4, r0 = tr * 4;
  float acc[4][4] = {};

  for (int kc = 0; kc < KDIM; kc += 32) {
    for (int q = t; q < 512; q += 256) {
      int node = q >> 3, f4 = q & 7;
      int gn = block_m + node;
      if (gn >= N) gn = N - 1;
      const float4 v = *(const float4*)(A + (size_t)gn * KDIM + kc + f4 * 4);
      As[f4 * 4 + 0][node] = v.x;
      As[f4 * 4 + 1][node] = v.y;
      As[f4 * 4 + 2][node] = v.z;
      As[f4 * 4 + 3][node] = v.w;
    }
    for (int q = t; q < 512; q += 256) {
      int k = q >> 4, f4 = q & 15;
      const float4 v = *(const float4*)(W + (size_t)(kc + k) * 64 + f4 * 4);
      *(float4*)&Ws[k][f4 * 4] = v;
    }
    __syncthreads();
#pragma unroll
    for (int k = 0; k < 32; ++k) {
      float4 a = *(const float4*)&As[k][r0];
      float4 b = *(const float4*)&Ws[k][c0];
      acc[0][0] += a.x * b.x; acc[0][1] += a.x * b.y; acc[0][2] += a.x * b.z; acc[0][3] += a.x * b.w;
      acc[1][0] += a.y * b.x; acc[1][1] += a.y * b.y; acc[1][2] += a.y * b.z; acc[1][3] += a.y * b.w;
      acc[2][0] += a.z * b.x; acc[2][1] += a.z * b.y; acc[2][2] += a.z * b.z; acc[2][3] += a.z * b.w;
      acc[3][0] += a.w * b.x; acc[3][1] += a.w * b.y; acc[3][2] += a.w * b.z; acc[3][3] += a.w * b.w;
    }
    __syncthreads();
  }
#pragma unroll
  for (int i = 0; i < 4; ++i) {
    int gn = block_m + r0 + i;
    if (gn < N) {
      float4 v = make_float4(acc[i][0], acc[i][1], acc[i][2], acc[i][3]);
      *(float4*)(C + (size_t)gn * 64 + c0) = v;
    }
  }
}

// al_src[n] = h[n,:] . a_src ; al_dst[n] = h[n,:] . a_dst   (wave per node)
__global__ void al_kernel(const float* __restrict__ h, const float* __restrict__ a_src,
                          const float* __restrict__ a_dst, float* __restrict__ alsrc,
                          float* __restrict__ aldst, int N) {
  int wid = (blockIdx.x * blockDim.x + threadIdx.x) >> 6;
  int lane = threadIdx.x & 63;
  if (wid >= N) return;
  float v = h[(size_t)wid * 64 + lane];
  float s1 = wave_reduce_sum(v * a_src[lane]);
  float s2 = wave_reduce_sum(v * a_dst[lane]);
  if (lane == 0) {
    alsrc[wid] = s1;
    aldst[wid] = s2;
  }
}

__global__ void logits_kernel(const int* __restrict__ csrc, const int* __restrict__ cdst,
                              const float* __restrict__ alsrc, const float* __restrict__ aldst,
                              float* __restrict__ logit, int M) {
  int t = blockIdx.x * blockDim.x + threadIdx.x;
  if (t >= M) return;
  float e = alsrc[csrc[t]] + aldst[cdst[t]];
  logit[t] = (e > 0.f) ? e : 0.2f * e;  // leaky_relu 0.2
}

// 16 lanes per node: segment softmax over the node's contiguous logit range,
// write per-edge coef = exp(lg - m) / ssum. No gathers — cheap.
__global__ void coef_kernel(const int* __restrict__ rowptr, const float* __restrict__ logit,
                            float* __restrict__ coef, int N) {
  int tid = blockIdx.x * blockDim.x + threadIdx.x;
  int node = tid >> 4;
  int sub = tid & 15;
  if (node >= N) return;
  int start = rowptr[node];
  int end = rowptr[node + 1];

  float m = -1e30f;
  for (int i = start + sub; i < end; i += 16) m = fmaxf(m, logit[i]);
#pragma unroll
  for (int off = 1; off < 16; off <<= 1) m = fmaxf(m, __shfl_xor(m, off, 64));

  float s = 0.f;
  for (int i = start + sub; i < end; i += 16) s += __expf(logit[i] - m);
#pragma unroll
  for (int off = 1; off < 16; off <<= 1) s += __shfl_xor(s, off, 64);

  float inv = 1.0f / s;  // >= 1 edge per node (self-loop)
  for (int i = start + sub; i < end; i += 16) coef[i] = __expf(logit[i] - m) * inv;
}

// Edge-parallel weighted gather-accumulate: acc[dst,:] += coef * h[src,:].
// Block stages 512 contiguous (src,dst,coef) into LDS; each 16-lane group
// walks 32 contiguous edges in packs of 4 (4 independent row loads in
// flight); dst-sorted input => register accumulation, atomic flush on
// dst change only. acc must be pre-zeroed.
#define SPMM_BLOCK_EDGES 512
__global__ __launch_bounds__(256) void spmm_kernel(const int* __restrict__ csrc,
                                                   const int* __restrict__ cdst,
                                                   const float* __restrict__ coef,
                                                   const float* __restrict__ h,
                                                   float* __restrict__ acc_out, int M) {
  __shared__ int sS[SPMM_BLOCK_EDGES];
  __shared__ int sD[SPMM_BLOCK_EDGES];
  __shared__ float sC[SPMM_BLOCK_EDGES];
  const int tid = threadIdx.x;
  const int blockBase = blockIdx.x * SPMM_BLOCK_EDGES;

  for (int i = tid; i < SPMM_BLOCK_EDGES; i += 256) {
    int gi = blockBase + i;
    if (gi < M) {
      sS[i] = csrc[gi];
      sD[i] = cdst[gi];
      sC[i] = coef[gi];
    }
  }
  __syncthreads();

  const int f4 = tid & 15;                     // float4 slot within row
  const int lbase = (tid >> 4) * 32;           // group's local edge base
  int n = M - (blockBase + lbase);
  n = (n < 0) ? 0 : ((n > 32) ? 32 : n);

  float4 acc = make_float4(0.f, 0.f, 0.f, 0.f);
  int cur = -1;

#define FLUSH()                                             \
  do {                                                      \
    float* o = acc_out + (size_t)cur * 64 + f4 * 4;         \
    atomicAdd(o + 0, acc.x);                                \
    atomicAdd(o + 1, acc.y);                                \
    atomicAdd(o + 2, acc.z);                                \
    atomicAdd(o + 3, acc.w);                                \
  } while (0)

  int e = 0;
  for (; e + 4 <= n; e += 4) {
    int li = lbase + e;
    int d0 = sD[li], d1 = sD[li + 1], d2 = sD[li + 2], d3 = sD[li + 3];
    int s0 = sS[li], s1 = sS[li + 1], s2 = sS[li + 2], s3 = sS[li + 3];
    float c0 = sC[li], c1 = sC[li + 1], c2 = sC[li + 2], c3 = sC[li + 3];
    const float4 r0 = *(const float4*)(h + (size_t)s0 * 64 + f4 * 4);
    const float4 r1 = *(const float4*)(h + (size_t)s1 * 64 + f4 * 4);
    const float4 r2 = *(const float4*)(h + (size_t)s2 * 64 + f4 * 4);
    const float4 r3 = *(const float4*)(h + (size_t)s3 * 64 + f4 * 4);
    if (d0 != cur) { if (cur >= 0) FLUSH(); cur = d0; acc = make_float4(0.f, 0.f, 0.f, 0.f); }
    acc.x += c0 * r0.x; acc.y += c0 * r0.y; acc.z += c0 * r0.z; acc.w += c0 * r0.w;
    if (d1 != cur) { FLUSH(); cur = d1; acc = make_float4(0.f, 0.f, 0.f, 0.f); }
    acc.x += c1 * r1.x; acc.y += c1 * r1.y; acc.z += c1 * r1.z; acc.w += c1 * r1.w;
    if (d2 != cur) { FLUSH(); cur = d2; acc = make_float4(0.f, 0.f, 0.f, 0.f); }
    acc.x += c2 * r2.x; acc.y += c2 * r2.y; acc.z += c2 * r2.z; acc.w += c2 * r2.w;
    if (d3 != cur) { FLUSH(); cur = d3; acc = make_float4(0.f, 0.f, 0.f, 0.f); }
    acc.x += c3 * r3.x; acc.y += c3 * r3.y; acc.z += c3 * r3.z; acc.w += c3 * r3.w;
  }
  for (; e < n; ++e) {
    int li = lbase + e;
    int d0 = sD[li];
    int s0 = sS[li];
    float c0 = sC[li];
    const float4 r0 = *(const float4*)(h + (size_t)s0 * 64 + f4 * 4);
    if (d0 != cur) { if (cur >= 0) FLUSH(); cur = d0; acc = make_float4(0.f, 0.f, 0.f, 0.f); }
    acc.x += c0 * r0.x; acc.y += c0 * r0.y; acc.z += c0 * r0.z; acc.w += c0 * r0.w;
  }
  if (cur >= 0) FLUSH();
#undef FLUSH
}

// bias + ELU epilogue. do_pool: atomicAdd into per-graph mean-pool buffer.
__global__ void post_kernel(const float* __restrict__ acc, const float* __restrict__ bias,
                            float* __restrict__ out, int N, int do_pool,
                            const int* __restrict__ batch, float* __restrict__ pool) {
  int t = blockIdx.x * blockDim.x + threadIdx.x;  // over N*16 float4s
  if (t >= N * 16) return;
  int node = t >> 4;
  int f4 = t & 15;
  float4 v = *(const float4*)(acc + (size_t)t * 4);
  const float4 b4 = *(const float4*)(bias + f4 * 4);
  v.x += b4.x; v.y += b4.y; v.z += b4.z; v.w += b4.w;
  v.x = (v.x > 0.f) ? v.x : expm1f(v.x);
  v.y = (v.y > 0.f) ? v.y : expm1f(v.y);
  v.z = (v.z > 0.f) ? v.z : expm1f(v.z);
  v.w = (v.w > 0.f) ? v.w : expm1f(v.w);
  if (!do_pool) {
    *(float4*)(out + (size_t)t * 4) = v;
  } else {
    float* p = pool + (size_t)batch[node] * 64 + f4 * 4;
    atomicAdd(p + 0, v.x);
    atomicAdd(p + 1, v.y);
    atomicAdd(p + 2, v.z);
    atomicAdd(p + 3, v.w);
  }
}

__global__ void cnt_kernel(const int* __restrict__ batch, float* __restrict__ cnt, int N) {
  int t = blockIdx.x * blockDim.x + threadIdx.x;
  if (t < N) atomicAdd(&cnt[batch[t]], 1.0f);
}

// out[g] = (pool[g,:]/cnt[g]) . Wfc + bfc    (wave per graph)
__global__ void final_kernel(const float* __restrict__ pool, const float* __restrict__ cnt,
                             const float* __restrict__ Wfc, const float* __restrict__ bfc,
                             float* __restrict__ out, int G) {
  int wid = (blockIdx.x * blockDim.x + threadIdx.x) >> 6;
  int lane = threadIdx.x & 63;
  if (wid >= G) return;
  float c = fmaxf(cnt[wid], 1.0f);
  float v = pool[(size_t)wid * 64 + lane] * (1.0f / c) * Wfc[lane];
  v = wave_reduce_sum(v);
  if (lane == 0) out[wid] = v + bfc[0];
}

// ---------------------------------------------------------------------------

extern "C" void kernel_launch(void* const* d_in, const int* in_sizes, int n_in,
                              void* d_out, int out_size, void* d_ws, size_t ws_size,
                              hipStream_t stream) {
  const float* x     = (const float*)d_in[0];
  const int*   ei    = (const int*)d_in[1];
  const int*   batch = (const int*)d_in[2];
  const float* W1    = (const float*)d_in[3];
  const float* asrc1 = (const float*)d_in[4];
  const float* adst1 = (const float*)d_in[5];
  const float* b1    = (const float*)d_in[6];
  const float* W2    = (const float*)d_in[7];
  const float* asrc2 = (const float*)d_in[8];
  const float* adst2 = (const float*)d_in[9];
  const float* b2    = (const float*)d_in[10];
  const float* Wfc   = (const float*)d_in[11];
  const float* bfc   = (const float*)d_in[12];
  float* out = (float*)d_out;

  const int N = in_sizes[0] / 128;  // 100000
  const int E = in_sizes[1] / 2;    // 1600000
  const int G = 256;
  const int M = E + N;              // edges incl self-loops

  // workspace carve (256B aligned)
  char* p = (char*)d_ws;
  auto alloc = [&](size_t bytes) {
    char* r = p;
    p += (bytes + 255) & ~size_t(255);
    return r;
  };
  float* h1     = (float*)alloc((size_t)N * 64 * 4);
  float* h1e    = (float*)alloc((size_t)N * 64 * 4);
  float* accbuf = (float*)alloc((size_t)N * 64 * 4);
  float* h2     = h1;  // h1 dead after layer-1 spmm; alias
  float* alsrc  = (float*)alloc((size_t)N * 4);
  float* aldst  = (float*)alloc((size_t)N * 4);
  int*   deg    = (int*)alloc((size_t)N * 4);
  int*   rowptr = (int*)alloc((size_t)(N + 1) * 4);
  int*   cursor = (int*)alloc((size_t)N * 4);
  int*   csrc   = (int*)alloc((size_t)M * 4);
  int*   cdst   = (int*)alloc((size_t)M * 4);
  float* logit  = (float*)alloc((size_t)M * 4);
  float* coef   = (float*)alloc((size_t)M * 4);
  float* pool   = (float*)alloc((size_t)G * 64 * 4);
  float* cnt    = (float*)alloc((size_t)G * 4);
  int*   partials = (int*)alloc(256 * 4);

  const int spmm_blocks = (M + SPMM_BLOCK_EDGES - 1) / SPMM_BLOCK_EDGES;

  // ---- CSR build (shared by both layers) ----
  hipMemsetAsync(deg, 0, (size_t)N * 4, stream);
  deg_kernel<<<(M + 255) / 256, 256, 0, stream>>>(ei, E, N, deg);
  int nb = (N + 2047) / 2048;
  scan1_kernel<<<nb, 256, 0, stream>>>(deg, rowptr, partials, N);
  scan2_kernel<<<1, 64, 0, stream>>>(partials, nb, rowptr + N);
  scan3_kernel<<<(N + 255) / 256, 256, 0, stream>>>(rowptr, partials, N);
  hipMemcpyAsync(cursor, rowptr, (size_t)N * 4, hipMemcpyDeviceToDevice, stream);
  scatter_kernel<<<(M + 255) / 256, 256, 0, stream>>>(ei, E, N, cursor, csrc, cdst);
  cnt_kernel<<<(N + 255) / 256, 256, 0, stream>>>(batch, cnt, N);  // cnt zero? no!

  // ---- layer 1 ----
  gemm64<128><<<(N + 63) / 64, 256, 0, stream>>>(x, W1, h1, N);
  al_kernel<<<(N * 64 + 255) / 256, 256, 0, stream>>>(h1, asrc1, adst1, alsrc, aldst, N);
  logits_kernel<<<(M + 255) / 256, 256, 0, stream>>>(csrc, cdst, alsrc, aldst, logit, M);
  coef_kernel<<<(N * 16 + 255) / 256, 256, 0, stream>>>(rowptr, logit, coef, N);
  hipMemsetAsync(accbuf, 0, (size_t)N * 64 * 4, stream);
  spmm_kernel<<<spmm_blocks, 256, 0, stream>>>(csrc, cdst, coef, h1, accbuf, M);
  post_kernel<<<(N * 16 + 255) / 256, 256, 0, stream>>>(accbuf, b1, h1e, N, 0, nullptr, nullptr);

  // ---- layer 2 (pooling fused into post) ----
  gemm64<64><<<(N + 63) / 64, 256, 0, stream>>>(h1e, W2, h2, N);
  al_kernel<<<(N * 64 + 255) / 256, 256, 0, stream>>>(h2, asrc2, adst2, alsrc, aldst, N);
  logits_kernel<<<(M + 255) / 256, 256, 0, stream>>>(csrc, cdst, alsrc, aldst, logit, M);
  coef_kernel<<<(N * 16 + 255) / 256, 256, 0, stream>>>(rowptr, logit, coef, N);
  hipMemsetAsync(accbuf, 0, (size_t)N * 64 * 4, stream);
  spmm_kernel<<<spmm_blocks, 256, 0, stream>>>(csrc, cdst, coef, h2, accbuf, M);
  hipMemsetAsync(pool, 0, (size_t)G * 64 * 4, stream);
  hipMemsetAsync(cnt, 0, (size_t)G * 4, stream);
  // cnt must be counted AFTER the zeroing (moved here; the early call above
  // operated on poisoned memory and is overwritten by this sequence):
  cnt_kernel<<<(N + 255) / 256, 256, 0, stream>>>(batch, cnt, N);
  post_kernel<<<(N * 16 + 255) / 256, 256, 0, stream>>>(accbuf, b2, nullptr, N, 1, batch, pool);

  // ---- readout ----
  final_kernel<<<(G * 64 + 255) / 256, 256, 0, stream>>>(pool, cnt, Wfc, bfc, out, G);
}

// Round 6
// 890.493 us; speedup vs baseline: 1.4237x; 1.4237x over previous
//
#include <hip/hip_runtime.h>
#include <hip/hip_bf16.h>
#include <cstdint>

// ---------------------------------------------------------------------------
// GAT 2-layer model on MI355X.
// R3: edge-parallel SpMM aggregation (coef -> spmm -> post).
// R4: passed; cnt_kernel (contended fp32 atomics, 2x193us) dominated.
// R5: deterministic pool_kernel variant FAILED the post-timing check with a
//     stable wrong output on repeat launches (mechanism unidentified).
// R6: minimal delta from R4 (last passing state): delete cnt_kernel entirely,
//     derive per-graph counts from binary-search bounds on the sorted batch
//     (integer-exact), keep R4's atomic pooled post_kernel path.
// ---------------------------------------------------------------------------

__device__ __forceinline__ float wave_reduce_sum(float v) {
#pragma unroll
  for (int off = 32; off > 0; off >>= 1) v += __shfl_xor(v, off, 64);
  return v;
}

// ---------------- CSR build ----------------

__global__ void deg_kernel(const int* __restrict__ ei, int E, int N,
                           int* __restrict__ deg) {
  int t = blockIdx.x * blockDim.x + threadIdx.x;
  int total = E + N;
  if (t >= total) return;
  int d = (t < E) ? ei[E + t] : (t - E);  // self loops appended
  atomicAdd(&deg[d], 1);
}

__global__ void scan1_kernel(const int* __restrict__ deg, int* __restrict__ rowptr,
                             int* __restrict__ partials, int n) {
  __shared__ int wsum[4];
  int t = threadIdx.x;
  int lane = t & 63, wv = t >> 6;
  int base = blockIdx.x * 2048 + t * 8;
  int v[8];
  int s = 0;
#pragma unroll
  for (int i = 0; i < 8; i++) {
    int idx = base + i;
    v[i] = (idx < n) ? deg[idx] : 0;
    s += v[i];
  }
  int x = s;
#pragma unroll
  for (int off = 1; off < 64; off <<= 1) {
    int u = __shfl_up(x, off, 64);
    if (lane >= off) x += u;
  }
  if (lane == 63) wsum[wv] = x;
  __syncthreads();
  int woff = 0;
  for (int j = 0; j < wv; j++) woff += wsum[j];
  int excl = woff + x - s;
#pragma unroll
  for (int i = 0; i < 8; i++) {
    int idx = base + i;
    if (idx < n) rowptr[idx] = excl;
    excl += v[i];
  }
  if (t == 255) partials[blockIdx.x] = woff + x;
}

__global__ void scan2_kernel(int* __restrict__ partials, int nb,
                             int* __restrict__ rowptr_end) {
  if (threadIdx.x == 0 && blockIdx.x == 0) {
    int run = 0;
    for (int i = 0; i < nb; i++) {
      int t = partials[i];
      partials[i] = run;
      run += t;
    }
    *rowptr_end = run;
  }
}

__global__ void scan3_kernel(int* __restrict__ rowptr, const int* __restrict__ partials,
                             int n) {
  int idx = blockIdx.x * blockDim.x + threadIdx.x;
  if (idx < n) rowptr[idx] += partials[idx >> 11];
}

__global__ void scatter_kernel(const int* __restrict__ ei, int E, int N,
                               int* __restrict__ cursor, int* __restrict__ csrc,
                               int* __restrict__ cdst) {
  int t = blockIdx.x * blockDim.x + threadIdx.x;
  int total = E + N;
  if (t >= total) return;
  int s, d;
  if (t < E) {
    s = ei[t];
    d = ei[E + t];
  } else {
    s = d = t - E;
  }
  int pos = atomicAdd(&cursor[d], 1);
  csrc[pos] = s;
  cdst[pos] = d;
}

// gstart[g] = first node index with batch[node] >= g (batch sorted), g in [0,256]
__global__ void bounds_kernel(const int* __restrict__ batch, int* __restrict__ gstart,
                              int N, int G) {
  int g = blockIdx.x * blockDim.x + threadIdx.x;
  if (g > G) return;
  int lo = 0, hi = N;
  while (lo < hi) {
    int mid = (lo + hi) >> 1;
    if (batch[mid] < g) lo = mid + 1;
    else hi = mid;
  }
  gstart[g] = lo;
}

// ---------------- dense compute ----------------

// C[N][64] = A[N][KDIM] @ W[KDIM][64], fp32, 64x64 tile, 4x4 microtile
template <int KDIM>
__global__ __launch_bounds__(256) void gemm64(const float* __restrict__ A,
                                              const float* __restrict__ W,
                                              float* __restrict__ C, int N) {
  __shared__ float As[32][68];
  __shared__ float Ws[32][68];
  const int block_m = blockIdx.x * 64;
  const int t = threadIdx.x;
  const int tc = t & 15;
  const int tr = t >> 4;
  const int c0 = tc * 4, r0 = tr * 4;
  float acc[4][4] = {};

  for (int kc = 0; kc < KDIM; kc += 32) {
    for (int q = t; q < 512; q += 256) {
      int node = q >> 3, f4 = q & 7;
      int gn = block_m + node;
      if (gn >= N) gn = N - 1;
      const float4 v = *(const float4*)(A + (size_t)gn * KDIM + kc + f4 * 4);
      As[f4 * 4 + 0][node] = v.x;
      As[f4 * 4 + 1][node] = v.y;
      As[f4 * 4 + 2][node] = v.z;
      As[f4 * 4 + 3][node] = v.w;
    }
    for (int q = t; q < 512; q += 256) {
      int k = q >> 4, f4 = q & 15;
      const float4 v = *(const float4*)(W + (size_t)(kc + k) * 64 + f4 * 4);
      *(float4*)&Ws[k][f4 * 4] = v;
    }
    __syncthreads();
#pragma unroll
    for (int k = 0; k < 32; ++k) {
      float4 a = *(const float4*)&As[k][r0];
      float4 b = *(const float4*)&Ws[k][c0];
      acc[0][0] += a.x * b.x; acc[0][1] += a.x * b.y; acc[0][2] += a.x * b.z; acc[0][3] += a.x * b.w;
      acc[1][0] += a.y * b.x; acc[1][1] += a.y * b.y; acc[1][2] += a.y * b.z; acc[1][3] += a.y * b.w;
      acc[2][0] += a.z * b.x; acc[2][1] += a.z * b.y; acc[2][2] += a.z * b.z; acc[2][3] += a.z * b.w;
      acc[3][0] += a.w * b.x; acc[3][1] += a.w * b.y; acc[3][2] += a.w * b.z; acc[3][3] += a.w * b.w;
    }
    __syncthreads();
  }
#pragma unroll
  for (int i = 0; i < 4; ++i) {
    int gn = block_m + r0 + i;
    if (gn < N) {
      float4 v = make_float4(acc[i][0], acc[i][1], acc[i][2], acc[i][3]);
      *(float4*)(C + (size_t)gn * 64 + c0) = v;
    }
  }
}

// al_src[n] = h[n,:] . a_src ; al_dst[n] = h[n,:] . a_dst   (wave per node)
__global__ void al_kernel(const float* __restrict__ h, const float* __restrict__ a_src,
                          const float* __restrict__ a_dst, float* __restrict__ alsrc,
                          float* __restrict__ aldst, int N) {
  int wid = (blockIdx.x * blockDim.x + threadIdx.x) >> 6;
  int lane = threadIdx.x & 63;
  if (wid >= N) return;
  float v = h[(size_t)wid * 64 + lane];
  float s1 = wave_reduce_sum(v * a_src[lane]);
  float s2 = wave_reduce_sum(v * a_dst[lane]);
  if (lane == 0) {
    alsrc[wid] = s1;
    aldst[wid] = s2;
  }
}

__global__ void logits_kernel(const int* __restrict__ csrc, const int* __restrict__ cdst,
                              const float* __restrict__ alsrc, const float* __restrict__ aldst,
                              float* __restrict__ logit, int M) {
  int t = blockIdx.x * blockDim.x + threadIdx.x;
  if (t >= M) return;
  float e = alsrc[csrc[t]] + aldst[cdst[t]];
  logit[t] = (e > 0.f) ? e : 0.2f * e;  // leaky_relu 0.2
}

// 16 lanes per node: segment softmax over the node's contiguous logit range,
// write per-edge coef = exp(lg - m) / ssum.
__global__ void coef_kernel(const int* __restrict__ rowptr, const float* __restrict__ logit,
                            float* __restrict__ coef, int N) {
  int tid = blockIdx.x * blockDim.x + threadIdx.x;
  int node = tid >> 4;
  int sub = tid & 15;
  if (node >= N) return;
  int start = rowptr[node];
  int end = rowptr[node + 1];

  float m = -1e30f;
  for (int i = start + sub; i < end; i += 16) m = fmaxf(m, logit[i]);
#pragma unroll
  for (int off = 1; off < 16; off <<= 1) m = fmaxf(m, __shfl_xor(m, off, 64));

  float s = 0.f;
  for (int i = start + sub; i < end; i += 16) s += __expf(logit[i] - m);
#pragma unroll
  for (int off = 1; off < 16; off <<= 1) s += __shfl_xor(s, off, 64);

  float inv = 1.0f / s;  // >= 1 edge per node (self-loop)
  for (int i = start + sub; i < end; i += 16) coef[i] = __expf(logit[i] - m) * inv;
}

// Edge-parallel weighted gather-accumulate: acc[dst,:] += coef * h[src,:].
#define SPMM_BLOCK_EDGES 512
__global__ __launch_bounds__(256) void spmm_kernel(const int* __restrict__ csrc,
                                                   const int* __restrict__ cdst,
                                                   const float* __restrict__ coef,
                                                   const float* __restrict__ h,
                                                   float* __restrict__ acc_out, int M) {
  __shared__ int sS[SPMM_BLOCK_EDGES];
  __shared__ int sD[SPMM_BLOCK_EDGES];
  __shared__ float sC[SPMM_BLOCK_EDGES];
  const int tid = threadIdx.x;
  const int blockBase = blockIdx.x * SPMM_BLOCK_EDGES;

  for (int i = tid; i < SPMM_BLOCK_EDGES; i += 256) {
    int gi = blockBase + i;
    if (gi < M) {
      sS[i] = csrc[gi];
      sD[i] = cdst[gi];
      sC[i] = coef[gi];
    }
  }
  __syncthreads();

  const int f4 = tid & 15;
  const int lbase = (tid >> 4) * 32;
  int n = M - (blockBase + lbase);
  n = (n < 0) ? 0 : ((n > 32) ? 32 : n);

  float4 acc = make_float4(0.f, 0.f, 0.f, 0.f);
  int cur = -1;

#define FLUSH()                                             \
  do {                                                      \
    float* o = acc_out + (size_t)cur * 64 + f4 * 4;         \
    atomicAdd(o + 0, acc.x);                                \
    atomicAdd(o + 1, acc.y);                                \
    atomicAdd(o + 2, acc.z);                                \
    atomicAdd(o + 3, acc.w);                                \
  } while (0)

  int e = 0;
  for (; e + 4 <= n; e += 4) {
    int li = lbase + e;
    int d0 = sD[li], d1 = sD[li + 1], d2 = sD[li + 2], d3 = sD[li + 3];
    int s0 = sS[li], s1 = sS[li + 1], s2 = sS[li + 2], s3 = sS[li + 3];
    float c0 = sC[li], c1 = sC[li + 1], c2 = sC[li + 2], c3 = sC[li + 3];
    const float4 r0 = *(const float4*)(h + (size_t)s0 * 64 + f4 * 4);
    const float4 r1 = *(const float4*)(h + (size_t)s1 * 64 + f4 * 4);
    const float4 r2 = *(const float4*)(h + (size_t)s2 * 64 + f4 * 4);
    const float4 r3 = *(const float4*)(h + (size_t)s3 * 64 + f4 * 4);
    if (d0 != cur) { if (cur >= 0) FLUSH(); cur = d0; acc = make_float4(0.f, 0.f, 0.f, 0.f); }
    acc.x += c0 * r0.x; acc.y += c0 * r0.y; acc.z += c0 * r0.z; acc.w += c0 * r0.w;
    if (d1 != cur) { FLUSH(); cur = d1; acc = make_float4(0.f, 0.f, 0.f, 0.f); }
    acc.x += c1 * r1.x; acc.y += c1 * r1.y; acc.z += c1 * r1.z; acc.w += c1 * r1.w;
    if (d2 != cur) { FLUSH(); cur = d2; acc = make_float4(0.f, 0.f, 0.f, 0.f); }
    acc.x += c2 * r2.x; acc.y += c2 * r2.y; acc.z += c2 * r2.z; acc.w += c2 * r2.w;
    if (d3 != cur) { FLUSH(); cur = d3; acc = make_float4(0.f, 0.f, 0.f, 0.f); }
    acc.x += c3 * r3.x; acc.y += c3 * r3.y; acc.z += c3 * r3.z; acc.w += c3 * r3.w;
  }
  for (; e < n; ++e) {
    int li = lbase + e;
    int d0 = sD[li];
    int s0 = sS[li];
    float c0 = sC[li];
    const float4 r0 = *(const float4*)(h + (size_t)s0 * 64 + f4 * 4);
    if (d0 != cur) { if (cur >= 0) FLUSH(); cur = d0; acc = make_float4(0.f, 0.f, 0.f, 0.f); }
    acc.x += c0 * r0.x; acc.y += c0 * r0.y; acc.z += c0 * r0.z; acc.w += c0 * r0.w;
  }
  if (cur >= 0) FLUSH();
#undef FLUSH
}

// bias + ELU epilogue. do_pool: atomicAdd into per-graph mean-pool buffer
// (R4's proven path).
__global__ void post_kernel(const float* __restrict__ acc, const float* __restrict__ bias,
                            float* __restrict__ out, int N, int do_pool,
                            const int* __restrict__ batch, float* __restrict__ pool) {
  int t = blockIdx.x * blockDim.x + threadIdx.x;  // over N*16 float4s
  if (t >= N * 16) return;
  int node = t >> 4;
  int f4 = t & 15;
  float4 v = *(const float4*)(acc + (size_t)t * 4);
  const float4 b4 = *(const float4*)(bias + f4 * 4);
  v.x += b4.x; v.y += b4.y; v.z += b4.z; v.w += b4.w;
  v.x = (v.x > 0.f) ? v.x : expm1f(v.x);
  v.y = (v.y > 0.f) ? v.y : expm1f(v.y);
  v.z = (v.z > 0.f) ? v.z : expm1f(v.z);
  v.w = (v.w > 0.f) ? v.w : expm1f(v.w);
  if (!do_pool) {
    *(float4*)(out + (size_t)t * 4) = v;
  } else {
    float* p = pool + (size_t)batch[node] * 64 + f4 * 4;
    atomicAdd(p + 0, v.x);
    atomicAdd(p + 1, v.y);
    atomicAdd(p + 2, v.z);
    atomicAdd(p + 3, v.w);
  }
}

// out[g] = (pool[g,:]/cnt[g]) . Wfc + bfc ; cnt derived from sorted-batch
// bounds (integer-exact, replaces the contended cnt_kernel atomics).
__global__ void final_kernel(const float* __restrict__ pool, const int* __restrict__ gstart,
                             const float* __restrict__ Wfc, const float* __restrict__ bfc,
                             float* __restrict__ out, int G) {
  int wid = (blockIdx.x * blockDim.x + threadIdx.x) >> 6;
  int lane = threadIdx.x & 63;
  if (wid >= G) return;
  float c = (float)max(gstart[wid + 1] - gstart[wid], 1);
  float v = pool[(size_t)wid * 64 + lane] * (1.0f / c) * Wfc[lane];
  v = wave_reduce_sum(v);
  if (lane == 0) out[wid] = v + bfc[0];
}

// ---------------------------------------------------------------------------

extern "C" void kernel_launch(void* const* d_in, const int* in_sizes, int n_in,
                              void* d_out, int out_size, void* d_ws, size_t ws_size,
                              hipStream_t stream) {
  const float* x     = (const float*)d_in[0];
  const int*   ei    = (const int*)d_in[1];
  const int*   batch = (const int*)d_in[2];
  const float* W1    = (const float*)d_in[3];
  const float* asrc1 = (const float*)d_in[4];
  const float* adst1 = (const float*)d_in[5];
  const float* b1    = (const float*)d_in[6];
  const float* W2    = (const float*)d_in[7];
  const float* asrc2 = (const float*)d_in[8];
  const float* adst2 = (const float*)d_in[9];
  const float* b2    = (const float*)d_in[10];
  const float* Wfc   = (const float*)d_in[11];
  const float* bfc   = (const float*)d_in[12];
  float* out = (float*)d_out;

  const int N = in_sizes[0] / 128;  // 100000
  const int E = in_sizes[1] / 2;    // 1600000
  const int G = 256;
  const int M = E + N;              // edges incl self-loops

  // workspace carve (256B aligned) — identical layout to R4, cnt -> gstart
  char* p = (char*)d_ws;
  auto alloc = [&](size_t bytes) {
    char* r = p;
    p += (bytes + 255) & ~size_t(255);
    return r;
  };
  float* h1     = (float*)alloc((size_t)N * 64 * 4);
  float* h1e    = (float*)alloc((size_t)N * 64 * 4);
  float* accbuf = (float*)alloc((size_t)N * 64 * 4);
  float* h2     = h1;  // h1 dead after layer-1 spmm; alias
  float* alsrc  = (float*)alloc((size_t)N * 4);
  float* aldst  = (float*)alloc((size_t)N * 4);
  int*   deg    = (int*)alloc((size_t)N * 4);
  int*   rowptr = (int*)alloc((size_t)(N + 1) * 4);
  int*   cursor = (int*)alloc((size_t)N * 4);
  int*   csrc   = (int*)alloc((size_t)M * 4);
  int*   cdst   = (int*)alloc((size_t)M * 4);
  float* logit  = (float*)alloc((size_t)M * 4);
  float* coef   = (float*)alloc((size_t)M * 4);
  float* pool   = (float*)alloc((size_t)G * 64 * 4);
  int*   gstart = (int*)alloc((size_t)(G + 1) * 4);
  int*   partials = (int*)alloc(256 * 4);

  const int spmm_blocks = (M + SPMM_BLOCK_EDGES - 1) / SPMM_BLOCK_EDGES;

  // ---- CSR build + graph bounds (shared by both layers) ----
  hipMemsetAsync(deg, 0, (size_t)N * 4, stream);
  deg_kernel<<<(M + 255) / 256, 256, 0, stream>>>(ei, E, N, deg);
  int nb = (N + 2047) / 2048;
  scan1_kernel<<<nb, 256, 0, stream>>>(deg, rowptr, partials, N);
  scan2_kernel<<<1, 64, 0, stream>>>(partials, nb, rowptr + N);
  scan3_kernel<<<(N + 255) / 256, 256, 0, stream>>>(rowptr, partials, N);
  hipMemcpyAsync(cursor, rowptr, (size_t)N * 4, hipMemcpyDeviceToDevice, stream);
  scatter_kernel<<<(M + 255) / 256, 256, 0, stream>>>(ei, E, N, cursor, csrc, cdst);
  bounds_kernel<<<2, 256, 0, stream>>>(batch, gstart, N, G);

  // ---- layer 1 ----
  gemm64<128><<<(N + 63) / 64, 256, 0, stream>>>(x, W1, h1, N);
  al_kernel<<<(N * 64 + 255) / 256, 256, 0, stream>>>(h1, asrc1, adst1, alsrc, aldst, N);
  logits_kernel<<<(M + 255) / 256, 256, 0, stream>>>(csrc, cdst, alsrc, aldst, logit, M);
  coef_kernel<<<(N * 16 + 255) / 256, 256, 0, stream>>>(rowptr, logit, coef, N);
  hipMemsetAsync(accbuf, 0, (size_t)N * 64 * 4, stream);
  spmm_kernel<<<spmm_blocks, 256, 0, stream>>>(csrc, cdst, coef, h1, accbuf, M);
  post_kernel<<<(N * 16 + 255) / 256, 256, 0, stream>>>(accbuf, b1, h1e, N, 0, nullptr, nullptr);

  // ---- layer 2 (pooling fused into post, R4 path) ----
  gemm64<64><<<(N + 63) / 64, 256, 0, stream>>>(h1e, W2, h2, N);
  al_kernel<<<(N * 64 + 255) / 256, 256, 0, stream>>>(h2, asrc2, adst2, alsrc, aldst, N);
  logits_kernel<<<(M + 255) / 256, 256, 0, stream>>>(csrc, cdst, alsrc, aldst, logit, M);
  coef_kernel<<<(N * 16 + 255) / 256, 256, 0, stream>>>(rowptr, logit, coef, N);
  hipMemsetAsync(accbuf, 0, (size_t)N * 64 * 4, stream);
  spmm_kernel<<<spmm_blocks, 256, 0, stream>>>(csrc, cdst, coef, h2, accbuf, M);
  hipMemsetAsync(pool, 0, (size_t)G * 64 * 4, stream);
  post_kernel<<<(N * 16 + 255) / 256, 256, 0, stream>>>(accbuf, b2, nullptr, N, 1, batch, pool);

  // ---- readout ----
  final_kernel<<<(G * 64 + 255) / 256, 256, 0, stream>>>(pool, gstart, Wfc, bfc, out, G);
}

// Round 7
// 737.885 us; speedup vs baseline: 1.7181x; 1.2068x over previous
//
#include <hip/hip_runtime.h>
#include <hip/hip_bf16.h>
#include <cstdint>

// ---------------------------------------------------------------------------
// GAT 2-layer model on MI355X.
// R3: edge-parallel SpMM aggregation (coef -> spmm -> post).
// R4/R6: passing baseline; pooled post_kernel = 25.6M fp32 atomics into 16k
//   addrs (~1560-deep) = 175us, WRITE_SIZE 102MB confirms per-lane atomics.
// R5 (failed): fully deterministic pool diverged post-timing; mechanism
//   unidentified — so we KEEP the atomic mechanism but cut atomic count 40x.
// R7: post_pool_kernel — block covers 16 sorted-batch nodes, LDS-stages the
//   ELU'd rows, reduces across nodes, 64 atomics per graph-uniform block
//   (~400k+260k boundary atomics total vs 25.6M).
// ---------------------------------------------------------------------------

__device__ __forceinline__ float wave_reduce_sum(float v) {
#pragma unroll
  for (int off = 32; off > 0; off >>= 1) v += __shfl_xor(v, off, 64);
  return v;
}

// ---------------- CSR build ----------------

__global__ void deg_kernel(const int* __restrict__ ei, int E, int N,
                           int* __restrict__ deg) {
  int t = blockIdx.x * blockDim.x + threadIdx.x;
  int total = E + N;
  if (t >= total) return;
  int d = (t < E) ? ei[E + t] : (t - E);  // self loops appended
  atomicAdd(&deg[d], 1);
}

__global__ void scan1_kernel(const int* __restrict__ deg, int* __restrict__ rowptr,
                             int* __restrict__ partials, int n) {
  __shared__ int wsum[4];
  int t = threadIdx.x;
  int lane = t & 63, wv = t >> 6;
  int base = blockIdx.x * 2048 + t * 8;
  int v[8];
  int s = 0;
#pragma unroll
  for (int i = 0; i < 8; i++) {
    int idx = base + i;
    v[i] = (idx < n) ? deg[idx] : 0;
    s += v[i];
  }
  int x = s;
#pragma unroll
  for (int off = 1; off < 64; off <<= 1) {
    int u = __shfl_up(x, off, 64);
    if (lane >= off) x += u;
  }
  if (lane == 63) wsum[wv] = x;
  __syncthreads();
  int woff = 0;
  for (int j = 0; j < wv; j++) woff += wsum[j];
  int excl = woff + x - s;
#pragma unroll
  for (int i = 0; i < 8; i++) {
    int idx = base + i;
    if (idx < n) rowptr[idx] = excl;
    excl += v[i];
  }
  if (t == 255) partials[blockIdx.x] = woff + x;
}

__global__ void scan2_kernel(int* __restrict__ partials, int nb,
                             int* __restrict__ rowptr_end) {
  if (threadIdx.x == 0 && blockIdx.x == 0) {
    int run = 0;
    for (int i = 0; i < nb; i++) {
      int t = partials[i];
      partials[i] = run;
      run += t;
    }
    *rowptr_end = run;
  }
}

__global__ void scan3_kernel(int* __restrict__ rowptr, const int* __restrict__ partials,
                             int n) {
  int idx = blockIdx.x * blockDim.x + threadIdx.x;
  if (idx < n) rowptr[idx] += partials[idx >> 11];
}

__global__ void scatter_kernel(const int* __restrict__ ei, int E, int N,
                               int* __restrict__ cursor, int* __restrict__ csrc,
                               int* __restrict__ cdst) {
  int t = blockIdx.x * blockDim.x + threadIdx.x;
  int total = E + N;
  if (t >= total) return;
  int s, d;
  if (t < E) {
    s = ei[t];
    d = ei[E + t];
  } else {
    s = d = t - E;
  }
  int pos = atomicAdd(&cursor[d], 1);
  csrc[pos] = s;
  cdst[pos] = d;
}

// gstart[g] = first node index with batch[node] >= g (batch sorted), g in [0,256]
__global__ void bounds_kernel(const int* __restrict__ batch, int* __restrict__ gstart,
                              int N, int G) {
  int g = blockIdx.x * blockDim.x + threadIdx.x;
  if (g > G) return;
  int lo = 0, hi = N;
  while (lo < hi) {
    int mid = (lo + hi) >> 1;
    if (batch[mid] < g) lo = mid + 1;
    else hi = mid;
  }
  gstart[g] = lo;
}

// ---------------- dense compute ----------------

// C[N][64] = A[N][KDIM] @ W[KDIM][64], fp32, 64x64 tile, 4x4 microtile
template <int KDIM>
__global__ __launch_bounds__(256) void gemm64(const float* __restrict__ A,
                                              const float* __restrict__ W,
                                              float* __restrict__ C, int N) {
  __shared__ float As[32][68];
  __shared__ float Ws[32][68];
  const int block_m = blockIdx.x * 64;
  const int t = threadIdx.x;
  const int tc = t & 15;
  const int tr = t >> 4;
  const int c0 = tc * 4, r0 = tr * 4;
  float acc[4][4] = {};

  for (int kc = 0; kc < KDIM; kc += 32) {
    for (int q = t; q < 512; q += 256) {
      int node = q >> 3, f4 = q & 7;
      int gn = block_m + node;
      if (gn >= N) gn = N - 1;
      const float4 v = *(const float4*)(A + (size_t)gn * KDIM + kc + f4 * 4);
      As[f4 * 4 + 0][node] = v.x;
      As[f4 * 4 + 1][node] = v.y;
      As[f4 * 4 + 2][node] = v.z;
      As[f4 * 4 + 3][node] = v.w;
    }
    for (int q = t; q < 512; q += 256) {
      int k = q >> 4, f4 = q & 15;
      const float4 v = *(const float4*)(W + (size_t)(kc + k) * 64 + f4 * 4);
      *(float4*)&Ws[k][f4 * 4] = v;
    }
    __syncthreads();
#pragma unroll
    for (int k = 0; k < 32; ++k) {
      float4 a = *(const float4*)&As[k][r0];
      float4 b = *(const float4*)&Ws[k][c0];
      acc[0][0] += a.x * b.x; acc[0][1] += a.x * b.y; acc[0][2] += a.x * b.z; acc[0][3] += a.x * b.w;
      acc[1][0] += a.y * b.x; acc[1][1] += a.y * b.y; acc[1][2] += a.y * b.z; acc[1][3] += a.y * b.w;
      acc[2][0] += a.z * b.x; acc[2][1] += a.z * b.y; acc[2][2] += a.z * b.z; acc[2][3] += a.z * b.w;
      acc[3][0] += a.w * b.x; acc[3][1] += a.w * b.y; acc[3][2] += a.w * b.z; acc[3][3] += a.w * b.w;
    }
    __syncthreads();
  }
#pragma unroll
  for (int i = 0; i < 4; ++i) {
    int gn = block_m + r0 + i;
    if (gn < N) {
      float4 v = make_float4(acc[i][0], acc[i][1], acc[i][2], acc[i][3]);
      *(float4*)(C + (size_t)gn * 64 + c0) = v;
    }
  }
}

// al_src[n] = h[n,:] . a_src ; al_dst[n] = h[n,:] . a_dst   (wave per node)
__global__ void al_kernel(const float* __restrict__ h, const float* __restrict__ a_src,
                          const float* __restrict__ a_dst, float* __restrict__ alsrc,
                          float* __restrict__ aldst, int N) {
  int wid = (blockIdx.x * blockDim.x + threadIdx.x) >> 6;
  int lane = threadIdx.x & 63;
  if (wid >= N) return;
  float v = h[(size_t)wid * 64 + lane];
  float s1 = wave_reduce_sum(v * a_src[lane]);
  float s2 = wave_reduce_sum(v * a_dst[lane]);
  if (lane == 0) {
    alsrc[wid] = s1;
    aldst[wid] = s2;
  }
}

__global__ void logits_kernel(const int* __restrict__ csrc, const int* __restrict__ cdst,
                              const float* __restrict__ alsrc, const float* __restrict__ aldst,
                              float* __restrict__ logit, int M) {
  int t = blockIdx.x * blockDim.x + threadIdx.x;
  if (t >= M) return;
  float e = alsrc[csrc[t]] + aldst[cdst[t]];
  logit[t] = (e > 0.f) ? e : 0.2f * e;  // leaky_relu 0.2
}

// 16 lanes per node: segment softmax over the node's contiguous logit range,
// write per-edge coef = exp(lg - m) / ssum.
__global__ void coef_kernel(const int* __restrict__ rowptr, const float* __restrict__ logit,
                            float* __restrict__ coef, int N) {
  int tid = blockIdx.x * blockDim.x + threadIdx.x;
  int node = tid >> 4;
  int sub = tid & 15;
  if (node >= N) return;
  int start = rowptr[node];
  int end = rowptr[node + 1];

  float m = -1e30f;
  for (int i = start + sub; i < end; i += 16) m = fmaxf(m, logit[i]);
#pragma unroll
  for (int off = 1; off < 16; off <<= 1) m = fmaxf(m, __shfl_xor(m, off, 64));

  float s = 0.f;
  for (int i = start + sub; i < end; i += 16) s += __expf(logit[i] - m);
#pragma unroll
  for (int off = 1; off < 16; off <<= 1) s += __shfl_xor(s, off, 64);

  float inv = 1.0f / s;  // >= 1 edge per node (self-loop)
  for (int i = start + sub; i < end; i += 16) coef[i] = __expf(logit[i] - m) * inv;
}

// Edge-parallel weighted gather-accumulate: acc[dst,:] += coef * h[src,:].
#define SPMM_BLOCK_EDGES 512
__global__ __launch_bounds__(256) void spmm_kernel(const int* __restrict__ csrc,
                                                   const int* __restrict__ cdst,
                                                   const float* __restrict__ coef,
                                                   const float* __restrict__ h,
                                                   float* __restrict__ acc_out, int M) {
  __shared__ int sS[SPMM_BLOCK_EDGES];
  __shared__ int sD[SPMM_BLOCK_EDGES];
  __shared__ float sC[SPMM_BLOCK_EDGES];
  const int tid = threadIdx.x;
  const int blockBase = blockIdx.x * SPMM_BLOCK_EDGES;

  for (int i = tid; i < SPMM_BLOCK_EDGES; i += 256) {
    int gi = blockBase + i;
    if (gi < M) {
      sS[i] = csrc[gi];
      sD[i] = cdst[gi];
      sC[i] = coef[gi];
    }
  }
  __syncthreads();

  const int f4 = tid & 15;
  const int lbase = (tid >> 4) * 32;
  int n = M - (blockBase + lbase);
  n = (n < 0) ? 0 : ((n > 32) ? 32 : n);

  float4 acc = make_float4(0.f, 0.f, 0.f, 0.f);
  int cur = -1;

#define FLUSH()                                             \
  do {                                                      \
    float* o = acc_out + (size_t)cur * 64 + f4 * 4;         \
    atomicAdd(o + 0, acc.x);                                \
    atomicAdd(o + 1, acc.y);                                \
    atomicAdd(o + 2, acc.z);                                \
    atomicAdd(o + 3, acc.w);                                \
  } while (0)

  int e = 0;
  for (; e + 4 <= n; e += 4) {
    int li = lbase + e;
    int d0 = sD[li], d1 = sD[li + 1], d2 = sD[li + 2], d3 = sD[li + 3];
    int s0 = sS[li], s1 = sS[li + 1], s2 = sS[li + 2], s3 = sS[li + 3];
    float c0 = sC[li], c1 = sC[li + 1], c2 = sC[li + 2], c3 = sC[li + 3];
    const float4 r0 = *(const float4*)(h + (size_t)s0 * 64 + f4 * 4);
    const float4 r1 = *(const float4*)(h + (size_t)s1 * 64 + f4 * 4);
    const float4 r2 = *(const float4*)(h + (size_t)s2 * 64 + f4 * 4);
    const float4 r3 = *(const float4*)(h + (size_t)s3 * 64 + f4 * 4);
    if (d0 != cur) { if (cur >= 0) FLUSH(); cur = d0; acc = make_float4(0.f, 0.f, 0.f, 0.f); }
    acc.x += c0 * r0.x; acc.y += c0 * r0.y; acc.z += c0 * r0.z; acc.w += c0 * r0.w;
    if (d1 != cur) { FLUSH(); cur = d1; acc = make_float4(0.f, 0.f, 0.f, 0.f); }
    acc.x += c1 * r1.x; acc.y += c1 * r1.y; acc.z += c1 * r1.z; acc.w += c1 * r1.w;
    if (d2 != cur) { FLUSH(); cur = d2; acc = make_float4(0.f, 0.f, 0.f, 0.f); }
    acc.x += c2 * r2.x; acc.y += c2 * r2.y; acc.z += c2 * r2.z; acc.w += c2 * r2.w;
    if (d3 != cur) { FLUSH(); cur = d3; acc = make_float4(0.f, 0.f, 0.f, 0.f); }
    acc.x += c3 * r3.x; acc.y += c3 * r3.y; acc.z += c3 * r3.z; acc.w += c3 * r3.w;
  }
  for (; e < n; ++e) {
    int li = lbase + e;
    int d0 = sD[li];
    int s0 = sS[li];
    float c0 = sC[li];
    const float4 r0 = *(const float4*)(h + (size_t)s0 * 64 + f4 * 4);
    if (d0 != cur) { if (cur >= 0) FLUSH(); cur = d0; acc = make_float4(0.f, 0.f, 0.f, 0.f); }
    acc.x += c0 * r0.x; acc.y += c0 * r0.y; acc.z += c0 * r0.z; acc.w += c0 * r0.w;
  }
  if (cur >= 0) FLUSH();
#undef FLUSH
}

// bias + ELU epilogue, dense write (layer 1).
__global__ void post_kernel(const float* __restrict__ acc, const float* __restrict__ bias,
                            float* __restrict__ out, int N) {
  int t = blockIdx.x * blockDim.x + threadIdx.x;  // over N*16 float4s
  if (t >= N * 16) return;
  int f4 = t & 15;
  float4 v = *(const float4*)(acc + (size_t)t * 4);
  const float4 b4 = *(const float4*)(bias + f4 * 4);
  v.x += b4.x; v.y += b4.y; v.z += b4.z; v.w += b4.w;
  v.x = (v.x > 0.f) ? v.x : expm1f(v.x);
  v.y = (v.y > 0.f) ? v.y : expm1f(v.y);
  v.z = (v.z > 0.f) ? v.z : expm1f(v.z);
  v.w = (v.w > 0.f) ? v.w : expm1f(v.w);
  *(float4*)(out + (size_t)t * 4) = v;
}

// bias + ELU + hierarchical mean-pool accumulation (layer 2).
// Block = 16 consecutive nodes x 16 f4-slots. batch sorted -> most blocks are
// graph-uniform: LDS-reduce across the 16 nodes, ONE atomicAdd per feature
// per block (64/block, ~400k total). Boundary blocks fall back to per-node
// atomics (~260k). vs 25.6M per-lane atomics in R6 (175us).
__global__ __launch_bounds__(256) void post_pool_kernel(
    const float* __restrict__ acc, const float* __restrict__ bias,
    const int* __restrict__ batch, float* __restrict__ pool, int N) {
  __shared__ float4 red4[16][17];  // [node][f4], stride 17 float4s (68 floats)
  __shared__ int sB[16];
  __shared__ int uni;
  const int t = threadIdx.x;
  const int ln = t >> 4;
  const int f4 = t & 15;
  const int base = blockIdx.x * 16;
  const int node = base + ln;

  if (t < 16) {
    int nn = base + t;
    sB[t] = (nn < N) ? batch[nn] : -1;
  }
  __syncthreads();
  if (t == 0) {
    int u = (base + 15 < N);
    for (int i = 1; i < 16; i++) u &= (sB[i] == sB[0]);
    uni = u;
  }

  float4 v = make_float4(0.f, 0.f, 0.f, 0.f);
  if (node < N) {
    v = *(const float4*)(acc + ((size_t)node * 16 + f4) * 4);
    const float4 b4 = *(const float4*)(bias + f4 * 4);
    v.x += b4.x; v.y += b4.y; v.z += b4.z; v.w += b4.w;
    v.x = (v.x > 0.f) ? v.x : expm1f(v.x);
    v.y = (v.y > 0.f) ? v.y : expm1f(v.y);
    v.z = (v.z > 0.f) ? v.z : expm1f(v.z);
    v.w = (v.w > 0.f) ? v.w : expm1f(v.w);
  }
  red4[ln][f4] = v;
  __syncthreads();  // covers red4 and uni

  if (t < 64) {
    const float* rf = (const float*)red4;  // row stride 68 floats
    if (uni) {
      float s = 0.f;
#pragma unroll
      for (int n = 0; n < 16; n++) s += rf[n * 68 + t];
      atomicAdd(&pool[(size_t)sB[0] * 64 + t], s);
    } else {
      for (int n = 0; n < 16; n++) {
        int g = sB[n];
        if (g >= 0) atomicAdd(&pool[(size_t)g * 64 + t], rf[n * 68 + t]);
      }
    }
  }
}

// out[g] = (pool[g,:]/cnt[g]) . Wfc + bfc ; cnt from sorted-batch bounds.
__global__ void final_kernel(const float* __restrict__ pool, const int* __restrict__ gstart,
                             const float* __restrict__ Wfc, const float* __restrict__ bfc,
                             float* __restrict__ out, int G) {
  int wid = (blockIdx.x * blockDim.x + threadIdx.x) >> 6;
  int lane = threadIdx.x & 63;
  if (wid >= G) return;
  float c = (float)max(gstart[wid + 1] - gstart[wid], 1);
  float v = pool[(size_t)wid * 64 + lane] * (1.0f / c) * Wfc[lane];
  v = wave_reduce_sum(v);
  if (lane == 0) out[wid] = v + bfc[0];
}

// ---------------------------------------------------------------------------

extern "C" void kernel_launch(void* const* d_in, const int* in_sizes, int n_in,
                              void* d_out, int out_size, void* d_ws, size_t ws_size,
                              hipStream_t stream) {
  const float* x     = (const float*)d_in[0];
  const int*   ei    = (const int*)d_in[1];
  const int*   batch = (const int*)d_in[2];
  const float* W1    = (const float*)d_in[3];
  const float* asrc1 = (const float*)d_in[4];
  const float* adst1 = (const float*)d_in[5];
  const float* b1    = (const float*)d_in[6];
  const float* W2    = (const float*)d_in[7];
  const float* asrc2 = (const float*)d_in[8];
  const float* adst2 = (const float*)d_in[9];
  const float* b2    = (const float*)d_in[10];
  const float* Wfc   = (const float*)d_in[11];
  const float* bfc   = (const float*)d_in[12];
  float* out = (float*)d_out;

  const int N = in_sizes[0] / 128;  // 100000
  const int E = in_sizes[1] / 2;    // 1600000
  const int G = 256;
  const int M = E + N;              // edges incl self-loops

  // workspace carve (256B aligned)
  char* p = (char*)d_ws;
  auto alloc = [&](size_t bytes) {
    char* r = p;
    p += (bytes + 255) & ~size_t(255);
    return r;
  };
  float* h1     = (float*)alloc((size_t)N * 64 * 4);
  float* h1e    = (float*)alloc((size_t)N * 64 * 4);
  float* accbuf = (float*)alloc((size_t)N * 64 * 4);
  float* h2     = h1;  // h1 dead after layer-1 spmm; alias
  float* alsrc  = (float*)alloc((size_t)N * 4);
  float* aldst  = (float*)alloc((size_t)N * 4);
  int*   deg    = (int*)alloc((size_t)N * 4);
  int*   rowptr = (int*)alloc((size_t)(N + 1) * 4);
  int*   cursor = (int*)alloc((size_t)N * 4);
  int*   csrc   = (int*)alloc((size_t)M * 4);
  int*   cdst   = (int*)alloc((size_t)M * 4);
  float* logit  = (float*)alloc((size_t)M * 4);
  float* coef   = (float*)alloc((size_t)M * 4);
  float* pool   = (float*)alloc((size_t)G * 64 * 4);
  int*   gstart = (int*)alloc((size_t)(G + 1) * 4);
  int*   partials = (int*)alloc(256 * 4);

  const int spmm_blocks = (M + SPMM_BLOCK_EDGES - 1) / SPMM_BLOCK_EDGES;

  // ---- CSR build + graph bounds (shared by both layers) ----
  hipMemsetAsync(deg, 0, (size_t)N * 4, stream);
  deg_kernel<<<(M + 255) / 256, 256, 0, stream>>>(ei, E, N, deg);
  int nb = (N + 2047) / 2048;
  scan1_kernel<<<nb, 256, 0, stream>>>(deg, rowptr, partials, N);
  scan2_kernel<<<1, 64, 0, stream>>>(partials, nb, rowptr + N);
  scan3_kernel<<<(N + 255) / 256, 256, 0, stream>>>(rowptr, partials, N);
  hipMemcpyAsync(cursor, rowptr, (size_t)N * 4, hipMemcpyDeviceToDevice, stream);
  scatter_kernel<<<(M + 255) / 256, 256, 0, stream>>>(ei, E, N, cursor, csrc, cdst);
  bounds_kernel<<<2, 256, 0, stream>>>(batch, gstart, N, G);

  // ---- layer 1 ----
  gemm64<128><<<(N + 63) / 64, 256, 0, stream>>>(x, W1, h1, N);
  al_kernel<<<(N * 64 + 255) / 256, 256, 0, stream>>>(h1, asrc1, adst1, alsrc, aldst, N);
  logits_kernel<<<(M + 255) / 256, 256, 0, stream>>>(csrc, cdst, alsrc, aldst, logit, M);
  coef_kernel<<<(N * 16 + 255) / 256, 256, 0, stream>>>(rowptr, logit, coef, N);
  hipMemsetAsync(accbuf, 0, (size_t)N * 64 * 4, stream);
  spmm_kernel<<<spmm_blocks, 256, 0, stream>>>(csrc, cdst, coef, h1, accbuf, M);
  post_kernel<<<(N * 16 + 255) / 256, 256, 0, stream>>>(accbuf, b1, h1e, N);

  // ---- layer 2 (hierarchical pooled post) ----
  gemm64<64><<<(N + 63) / 64, 256, 0, stream>>>(h1e, W2, h2, N);
  al_kernel<<<(N * 64 + 255) / 256, 256, 0, stream>>>(h2, asrc2, adst2, alsrc, aldst, N);
  logits_kernel<<<(M + 255) / 256, 256, 0, stream>>>(csrc, cdst, alsrc, aldst, logit, M);
  coef_kernel<<<(N * 16 + 255) / 256, 256, 0, stream>>>(rowptr, logit, coef, N);
  hipMemsetAsync(accbuf, 0, (size_t)N * 64 * 4, stream);
  spmm_kernel<<<spmm_blocks, 256, 0, stream>>>(csrc, cdst, coef, h2, accbuf, M);
  hipMemsetAsync(pool, 0, (size_t)G * 64 * 4, stream);
  post_pool_kernel<<<(N + 15) / 16, 256, 0, stream>>>(accbuf, b2, batch, pool, N);

  // ---- readout ----
  final_kernel<<<(G * 64 + 255) / 256, 256, 0, stream>>>(pool, gstart, Wfc, bfc, out, G);
}

// Round 8
// 690.852 us; speedup vs baseline: 1.8351x; 1.0681x over previous
//
#include <hip/hip_runtime.h>
#include <hip/hip_bf16.h>
#include <cstdint>

// ---------------------------------------------------------------------------
// GAT 2-layer model on MI355X.
// R7: spmm is the wall: 142us x2, FETCH 190MB (= 435MB logical fp32 gather at
//     ~56% L2 hit), WRITE 150MB, VALUBusy 5.5% -> pure traffic bound.
// R8: (1) h stored ONLY as bf16 (halves gather bytes); attention path stays
//     fp32: al_src/al_dst computed in the gemm epilogue from fp32 accs.
//     (2) logits fused into coef_kernel (one edge pass saved).
//     (3) spmm gathers ushort4 bf16 rows, converts in-register, fp32 accum;
//     atomic flush mechanism unchanged (R5's deterministic pool diverged
//     post-timing, so we keep the proven atomics).
// ---------------------------------------------------------------------------

__device__ __forceinline__ float wave_reduce_sum(float v) {
#pragma unroll
  for (int off = 32; off > 0; off >>= 1) v += __shfl_xor(v, off, 64);
  return v;
}

__device__ __forceinline__ unsigned short f2bf(float f) {  // RNE
  unsigned int u = __float_as_uint(f);
  u += 0x7fffu + ((u >> 16) & 1u);
  return (unsigned short)(u >> 16);
}
__device__ __forceinline__ float bf2f(unsigned short u) {
  return __uint_as_float(((unsigned int)u) << 16);
}

// ---------------- CSR build ----------------

__global__ void deg_kernel(const int* __restrict__ ei, int E, int N,
                           int* __restrict__ deg) {
  int t = blockIdx.x * blockDim.x + threadIdx.x;
  int total = E + N;
  if (t >= total) return;
  int d = (t < E) ? ei[E + t] : (t - E);  // self loops appended
  atomicAdd(&deg[d], 1);
}

__global__ void scan1_kernel(const int* __restrict__ deg, int* __restrict__ rowptr,
                             int* __restrict__ partials, int n) {
  __shared__ int wsum[4];
  int t = threadIdx.x;
  int lane = t & 63, wv = t >> 6;
  int base = blockIdx.x * 2048 + t * 8;
  int v[8];
  int s = 0;
#pragma unroll
  for (int i = 0; i < 8; i++) {
    int idx = base + i;
    v[i] = (idx < n) ? deg[idx] : 0;
    s += v[i];
  }
  int x = s;
#pragma unroll
  for (int off = 1; off < 64; off <<= 1) {
    int u = __shfl_up(x, off, 64);
    if (lane >= off) x += u;
  }
  if (lane == 63) wsum[wv] = x;
  __syncthreads();
  int woff = 0;
  for (int j = 0; j < wv; j++) woff += wsum[j];
  int excl = woff + x - s;
#pragma unroll
  for (int i = 0; i < 8; i++) {
    int idx = base + i;
    if (idx < n) rowptr[idx] = excl;
    excl += v[i];
  }
  if (t == 255) partials[blockIdx.x] = woff + x;
}

__global__ void scan2_kernel(int* __restrict__ partials, int nb,
                             int* __restrict__ rowptr_end) {
  if (threadIdx.x == 0 && blockIdx.x == 0) {
    int run = 0;
    for (int i = 0; i < nb; i++) {
      int t = partials[i];
      partials[i] = run;
      run += t;
    }
    *rowptr_end = run;
  }
}

__global__ void scan3_kernel(int* __restrict__ rowptr, const int* __restrict__ partials,
                             int n) {
  int idx = blockIdx.x * blockDim.x + threadIdx.x;
  if (idx < n) rowptr[idx] += partials[idx >> 11];
}

__global__ void scatter_kernel(const int* __restrict__ ei, int E, int N,
                               int* __restrict__ cursor, int* __restrict__ csrc,
                               int* __restrict__ cdst) {
  int t = blockIdx.x * blockDim.x + threadIdx.x;
  int total = E + N;
  if (t >= total) return;
  int s, d;
  if (t < E) {
    s = ei[t];
    d = ei[E + t];
  } else {
    s = d = t - E;
  }
  int pos = atomicAdd(&cursor[d], 1);
  csrc[pos] = s;
  cdst[pos] = d;
}

// gstart[g] = first node index with batch[node] >= g (batch sorted)
__global__ void bounds_kernel(const int* __restrict__ batch, int* __restrict__ gstart,
                              int N, int G) {
  int g = blockIdx.x * blockDim.x + threadIdx.x;
  if (g > G) return;
  int lo = 0, hi = N;
  while (lo < hi) {
    int mid = (lo + hi) >> 1;
    if (batch[mid] < g) lo = mid + 1;
    else hi = mid;
  }
  gstart[g] = lo;
}

// ---------------- dense compute ----------------

// hb[N][64] (bf16) = A[N][KDIM] @ W[KDIM][64]; also fused al epilogue:
// alsrc[n] = row . a_src, aldst[n] = row . a_dst, from the EXACT fp32 accs.
template <int KDIM>
__global__ __launch_bounds__(256) void gemm64(const float* __restrict__ A,
                                              const float* __restrict__ W,
                                              unsigned short* __restrict__ hb,
                                              const float* __restrict__ a_src,
                                              const float* __restrict__ a_dst,
                                              float* __restrict__ alsrc,
                                              float* __restrict__ aldst, int N) {
  __shared__ float As[32][68];
  __shared__ float Ws[32][68];
  const int block_m = blockIdx.x * 64;
  const int t = threadIdx.x;
  const int tc = t & 15;
  const int tr = t >> 4;
  const int c0 = tc * 4, r0 = tr * 4;
  float acc[4][4] = {};

  for (int kc = 0; kc < KDIM; kc += 32) {
    for (int q = t; q < 512; q += 256) {
      int node = q >> 3, f4 = q & 7;
      int gn = block_m + node;
      if (gn >= N) gn = N - 1;
      const float4 v = *(const float4*)(A + (size_t)gn * KDIM + kc + f4 * 4);
      As[f4 * 4 + 0][node] = v.x;
      As[f4 * 4 + 1][node] = v.y;
      As[f4 * 4 + 2][node] = v.z;
      As[f4 * 4 + 3][node] = v.w;
    }
    for (int q = t; q < 512; q += 256) {
      int k = q >> 4, f4 = q & 15;
      const float4 v = *(const float4*)(W + (size_t)(kc + k) * 64 + f4 * 4);
      *(float4*)&Ws[k][f4 * 4] = v;
    }
    __syncthreads();
#pragma unroll
    for (int k = 0; k < 32; ++k) {
      float4 a = *(const float4*)&As[k][r0];
      float4 b = *(const float4*)&Ws[k][c0];
      acc[0][0] += a.x * b.x; acc[0][1] += a.x * b.y; acc[0][2] += a.x * b.z; acc[0][3] += a.x * b.w;
      acc[1][0] += a.y * b.x; acc[1][1] += a.y * b.y; acc[1][2] += a.y * b.z; acc[1][3] += a.y * b.w;
      acc[2][0] += a.z * b.x; acc[2][1] += a.z * b.y; acc[2][2] += a.z * b.z; acc[2][3] += a.z * b.w;
      acc[3][0] += a.w * b.x; acc[3][1] += a.w * b.y; acc[3][2] += a.w * b.z; acc[3][3] += a.w * b.w;
    }
    __syncthreads();
  }

  const float as0 = a_src[c0], as1 = a_src[c0 + 1], as2 = a_src[c0 + 2], as3 = a_src[c0 + 3];
  const float ad0 = a_dst[c0], ad1 = a_dst[c0 + 1], ad2 = a_dst[c0 + 2], ad3 = a_dst[c0 + 3];
#pragma unroll
  for (int i = 0; i < 4; ++i) {
    int gn = block_m + r0 + i;
    // bf16 row store (16 lanes x 8B = one 128B row)
    if (gn < N) {
      ushort4 u;
      u.x = f2bf(acc[i][0]); u.y = f2bf(acc[i][1]);
      u.z = f2bf(acc[i][2]); u.w = f2bf(acc[i][3]);
      *(ushort4*)(hb + (size_t)gn * 64 + c0) = u;
    }
    // fused al: reduce over the 16 tc-lanes holding this row (low 4 lane bits)
    float ps = acc[i][0] * as0 + acc[i][1] * as1 + acc[i][2] * as2 + acc[i][3] * as3;
    float pd = acc[i][0] * ad0 + acc[i][1] * ad1 + acc[i][2] * ad2 + acc[i][3] * ad3;
#pragma unroll
    for (int off = 1; off < 16; off <<= 1) {
      ps += __shfl_xor(ps, off, 64);
      pd += __shfl_xor(pd, off, 64);
    }
    if (tc == 0 && gn < N) {
      alsrc[gn] = ps;
      aldst[gn] = pd;
    }
  }
}

// 16 lanes per node: fused logit computation (leaky(alsrc[src]+aldst[node]))
// + segment softmax; writes per-edge coef. logit buffer is scratch.
__global__ void coef_kernel(const int* __restrict__ rowptr, const int* __restrict__ csrc,
                            const float* __restrict__ alsrc, const float* __restrict__ aldst,
                            float* __restrict__ logit, float* __restrict__ coef, int N) {
  int tid = blockIdx.x * blockDim.x + threadIdx.x;
  int node = tid >> 4;
  int sub = tid & 15;
  if (node >= N) return;
  int start = rowptr[node];
  int end = rowptr[node + 1];
  float ad = aldst[node];

  float m = -1e30f;
  for (int i = start + sub; i < end; i += 16) {
    float e = alsrc[csrc[i]] + ad;
    e = (e > 0.f) ? e : 0.2f * e;  // leaky_relu 0.2
    logit[i] = e;
    m = fmaxf(m, e);
  }
#pragma unroll
  for (int off = 1; off < 16; off <<= 1) m = fmaxf(m, __shfl_xor(m, off, 64));

  float s = 0.f;
  for (int i = start + sub; i < end; i += 16) s += __expf(logit[i] - m);
#pragma unroll
  for (int off = 1; off < 16; off <<= 1) s += __shfl_xor(s, off, 64);

  float inv = 1.0f / s;  // >= 1 edge per node (self-loop)
  for (int i = start + sub; i < end; i += 16) coef[i] = __expf(logit[i] - m) * inv;
}

// Edge-parallel weighted gather-accumulate: acc[dst,:] += coef * hb[src,:].
// bf16 rows (128B), fp32 accumulate, atomic flush on dst change.
#define SPMM_BLOCK_EDGES 512
__global__ __launch_bounds__(256) void spmm_kernel(const int* __restrict__ csrc,
                                                   const int* __restrict__ cdst,
                                                   const float* __restrict__ coef,
                                                   const unsigned short* __restrict__ hb,
                                                   float* __restrict__ acc_out, int M) {
  __shared__ int sS[SPMM_BLOCK_EDGES];
  __shared__ int sD[SPMM_BLOCK_EDGES];
  __shared__ float sC[SPMM_BLOCK_EDGES];
  const int tid = threadIdx.x;
  const int blockBase = blockIdx.x * SPMM_BLOCK_EDGES;

  for (int i = tid; i < SPMM_BLOCK_EDGES; i += 256) {
    int gi = blockBase + i;
    if (gi < M) {
      sS[i] = csrc[gi];
      sD[i] = cdst[gi];
      sC[i] = coef[gi];
    }
  }
  __syncthreads();

  const int f4 = tid & 15;
  const int lbase = (tid >> 4) * 32;
  int n = M - (blockBase + lbase);
  n = (n < 0) ? 0 : ((n > 32) ? 32 : n);

  float4 acc = make_float4(0.f, 0.f, 0.f, 0.f);
  int cur = -1;

#define FLUSH()                                             \
  do {                                                      \
    float* o = acc_out + (size_t)cur * 64 + f4 * 4;         \
    atomicAdd(o + 0, acc.x);                                \
    atomicAdd(o + 1, acc.y);                                \
    atomicAdd(o + 2, acc.z);                                \
    atomicAdd(o + 3, acc.w);                                \
  } while (0)
#define GLOAD(dst4, sidx)                                                \
  float4 dst4;                                                           \
  {                                                                      \
    const ushort4 u = *(const ushort4*)(hb + (size_t)(sidx)*64 + f4 * 4); \
    dst4 = make_float4(bf2f(u.x), bf2f(u.y), bf2f(u.z), bf2f(u.w));      \
  }

  int e = 0;
  for (; e + 4 <= n; e += 4) {
    int li = lbase + e;
    int d0 = sD[li], d1 = sD[li + 1], d2 = sD[li + 2], d3 = sD[li + 3];
    int s0 = sS[li], s1 = sS[li + 1], s2 = sS[li + 2], s3 = sS[li + 3];
    float c0 = sC[li], c1 = sC[li + 1], c2 = sC[li + 2], c3 = sC[li + 3];
    GLOAD(r0, s0);
    GLOAD(r1, s1);
    GLOAD(r2, s2);
    GLOAD(r3, s3);
    if (d0 != cur) { if (cur >= 0) FLUSH(); cur = d0; acc = make_float4(0.f, 0.f, 0.f, 0.f); }
    acc.x += c0 * r0.x; acc.y += c0 * r0.y; acc.z += c0 * r0.z; acc.w += c0 * r0.w;
    if (d1 != cur) { FLUSH(); cur = d1; acc = make_float4(0.f, 0.f, 0.f, 0.f); }
    acc.x += c1 * r1.x; acc.y += c1 * r1.y; acc.z += c1 * r1.z; acc.w += c1 * r1.w;
    if (d2 != cur) { FLUSH(); cur = d2; acc = make_float4(0.f, 0.f, 0.f, 0.f); }
    acc.x += c2 * r2.x; acc.y += c2 * r2.y; acc.z += c2 * r2.z; acc.w += c2 * r2.w;
    if (d3 != cur) { FLUSH(); cur = d3; acc = make_float4(0.f, 0.f, 0.f, 0.f); }
    acc.x += c3 * r3.x; acc.y += c3 * r3.y; acc.z += c3 * r3.z; acc.w += c3 * r3.w;
  }
  for (; e < n; ++e) {
    int li = lbase + e;
    int d0 = sD[li];
    int s0 = sS[li];
    float c0 = sC[li];
    GLOAD(r0, s0);
    if (d0 != cur) { if (cur >= 0) FLUSH(); cur = d0; acc = make_float4(0.f, 0.f, 0.f, 0.f); }
    acc.x += c0 * r0.x; acc.y += c0 * r0.y; acc.z += c0 * r0.z; acc.w += c0 * r0.w;
  }
  if (cur >= 0) FLUSH();
#undef GLOAD
#undef FLUSH
}

// bias + ELU epilogue, dense fp32 write (layer 1 -> gemm2 input).
__global__ void post_kernel(const float* __restrict__ acc, const float* __restrict__ bias,
                            float* __restrict__ out, int N) {
  int t = blockIdx.x * blockDim.x + threadIdx.x;  // over N*16 float4s
  if (t >= N * 16) return;
  int f4 = t & 15;
  float4 v = *(const float4*)(acc + (size_t)t * 4);
  const float4 b4 = *(const float4*)(bias + f4 * 4);
  v.x += b4.x; v.y += b4.y; v.z += b4.z; v.w += b4.w;
  v.x = (v.x > 0.f) ? v.x : expm1f(v.x);
  v.y = (v.y > 0.f) ? v.y : expm1f(v.y);
  v.z = (v.z > 0.f) ? v.z : expm1f(v.z);
  v.w = (v.w > 0.f) ? v.w : expm1f(v.w);
  *(float4*)(out + (size_t)t * 4) = v;
}

// bias + ELU + hierarchical mean-pool accumulation (layer 2). See R7 notes.
__global__ __launch_bounds__(256) void post_pool_kernel(
    const float* __restrict__ acc, const float* __restrict__ bias,
    const int* __restrict__ batch, float* __restrict__ pool, int N) {
  __shared__ float4 red4[16][17];
  __shared__ int sB[16];
  __shared__ int uni;
  const int t = threadIdx.x;
  const int ln = t >> 4;
  const int f4 = t & 15;
  const int base = blockIdx.x * 16;
  const int node = base + ln;

  if (t < 16) {
    int nn = base + t;
    sB[t] = (nn < N) ? batch[nn] : -1;
  }
  __syncthreads();
  if (t == 0) {
    int u = (base + 15 < N);
    for (int i = 1; i < 16; i++) u &= (sB[i] == sB[0]);
    uni = u;
  }

  float4 v = make_float4(0.f, 0.f, 0.f, 0.f);
  if (node < N) {
    v = *(const float4*)(acc + ((size_t)node * 16 + f4) * 4);
    const float4 b4 = *(const float4*)(bias + f4 * 4);
    v.x += b4.x; v.y += b4.y; v.z += b4.z; v.w += b4.w;
    v.x = (v.x > 0.f) ? v.x : expm1f(v.x);
    v.y = (v.y > 0.f) ? v.y : expm1f(v.y);
    v.z = (v.z > 0.f) ? v.z : expm1f(v.z);
    v.w = (v.w > 0.f) ? v.w : expm1f(v.w);
  }
  red4[ln][f4] = v;
  __syncthreads();

  if (t < 64) {
    const float* rf = (const float*)red4;  // row stride 68 floats
    if (uni) {
      float s = 0.f;
#pragma unroll
      for (int n = 0; n < 16; n++) s += rf[n * 68 + t];
      atomicAdd(&pool[(size_t)sB[0] * 64 + t], s);
    } else {
      for (int n = 0; n < 16; n++) {
        int g = sB[n];
        if (g >= 0) atomicAdd(&pool[(size_t)g * 64 + t], rf[n * 68 + t]);
      }
    }
  }
}

// out[g] = (pool[g,:]/cnt[g]) . Wfc + bfc ; cnt from sorted-batch bounds.
__global__ void final_kernel(const float* __restrict__ pool, const int* __restrict__ gstart,
                             const float* __restrict__ Wfc, const float* __restrict__ bfc,
                             float* __restrict__ out, int G) {
  int wid = (blockIdx.x * blockDim.x + threadIdx.x) >> 6;
  int lane = threadIdx.x & 63;
  if (wid >= G) return;
  float c = (float)max(gstart[wid + 1] - gstart[wid], 1);
  float v = pool[(size_t)wid * 64 + lane] * (1.0f / c) * Wfc[lane];
  v = wave_reduce_sum(v);
  if (lane == 0) out[wid] = v + bfc[0];
}

// ---------------------------------------------------------------------------

extern "C" void kernel_launch(void* const* d_in, const int* in_sizes, int n_in,
                              void* d_out, int out_size, void* d_ws, size_t ws_size,
                              hipStream_t stream) {
  const float* x     = (const float*)d_in[0];
  const int*   ei    = (const int*)d_in[1];
  const int*   batch = (const int*)d_in[2];
  const float* W1    = (const float*)d_in[3];
  const float* asrc1 = (const float*)d_in[4];
  const float* adst1 = (const float*)d_in[5];
  const float* b1    = (const float*)d_in[6];
  const float* W2    = (const float*)d_in[7];
  const float* asrc2 = (const float*)d_in[8];
  const float* adst2 = (const float*)d_in[9];
  const float* b2    = (const float*)d_in[10];
  const float* Wfc   = (const float*)d_in[11];
  const float* bfc   = (const float*)d_in[12];
  float* out = (float*)d_out;

  const int N = in_sizes[0] / 128;  // 100000
  const int E = in_sizes[1] / 2;    // 1600000
  const int G = 256;
  const int M = E + N;              // edges incl self-loops

  // workspace carve (256B aligned)
  char* p = (char*)d_ws;
  auto alloc = [&](size_t bytes) {
    char* r = p;
    p += (bytes + 255) & ~size_t(255);
    return r;
  };
  float*          h1e    = (float*)alloc((size_t)N * 64 * 4);
  float*          accbuf = (float*)alloc((size_t)N * 64 * 4);
  unsigned short* hb     = (unsigned short*)alloc((size_t)N * 64 * 2);
  float* alsrc  = (float*)alloc((size_t)N * 4);
  float* aldst  = (float*)alloc((size_t)N * 4);
  int*   deg    = (int*)alloc((size_t)N * 4);
  int*   rowptr = (int*)alloc((size_t)(N + 1) * 4);
  int*   cursor = (int*)alloc((size_t)N * 4);
  int*   csrc   = (int*)alloc((size_t)M * 4);
  int*   cdst   = (int*)alloc((size_t)M * 4);
  float* logit  = (float*)alloc((size_t)M * 4);
  float* coef   = (float*)alloc((size_t)M * 4);
  float* pool   = (float*)alloc((size_t)G * 64 * 4);
  int*   gstart = (int*)alloc((size_t)(G + 1) * 4);
  int*   partials = (int*)alloc(256 * 4);

  const int spmm_blocks = (M + SPMM_BLOCK_EDGES - 1) / SPMM_BLOCK_EDGES;

  // ---- CSR build + graph bounds (shared by both layers) ----
  hipMemsetAsync(deg, 0, (size_t)N * 4, stream);
  deg_kernel<<<(M + 255) / 256, 256, 0, stream>>>(ei, E, N, deg);
  int nb = (N + 2047) / 2048;
  scan1_kernel<<<nb, 256, 0, stream>>>(deg, rowptr, partials, N);
  scan2_kernel<<<1, 64, 0, stream>>>(partials, nb, rowptr + N);
  scan3_kernel<<<(N + 255) / 256, 256, 0, stream>>>(rowptr, partials, N);
  hipMemcpyAsync(cursor, rowptr, (size_t)N * 4, hipMemcpyDeviceToDevice, stream);
  scatter_kernel<<<(M + 255) / 256, 256, 0, stream>>>(ei, E, N, cursor, csrc, cdst);
  bounds_kernel<<<2, 256, 0, stream>>>(batch, gstart, N, G);

  // ---- layer 1 ----
  gemm64<128><<<(N + 63) / 64, 256, 0, stream>>>(x, W1, hb, asrc1, adst1, alsrc, aldst, N);
  coef_kernel<<<(N * 16 + 255) / 256, 256, 0, stream>>>(rowptr, csrc, alsrc, aldst, logit, coef, N);
  hipMemsetAsync(accbuf, 0, (size_t)N * 64 * 4, stream);
  spmm_kernel<<<spmm_blocks, 256, 0, stream>>>(csrc, cdst, coef, hb, accbuf, M);
  post_kernel<<<(N * 16 + 255) / 256, 256, 0, stream>>>(accbuf, b1, h1e, N);

  // ---- layer 2 ----
  gemm64<64><<<(N + 63) / 64, 256, 0, stream>>>(h1e, W2, hb, asrc2, adst2, alsrc, aldst, N);
  coef_kernel<<<(N * 16 + 255) / 256, 256, 0, stream>>>(rowptr, csrc, alsrc, aldst, logit, coef, N);
  hipMemsetAsync(accbuf, 0, (size_t)N * 64 * 4, stream);
  spmm_kernel<<<spmm_blocks, 256, 0, stream>>>(csrc, cdst, coef, hb, accbuf, M);
  hipMemsetAsync(pool, 0, (size_t)G * 64 * 4, stream);
  post_pool_kernel<<<(N + 15) / 16, 256, 0, stream>>>(accbuf, b2, batch, pool, N);

  // ---- readout ----
  final_kernel<<<(G * 64 + 255) / 256, 256, 0, stream>>>(pool, gstart, Wfc, bfc, out, G);
}

// Round 9
// 473.824 us; speedup vs baseline: 2.6757x; 1.4580x over previous
//
#include <hip/hip_runtime.h>
#include <hip/hip_bf16.h>
#include <cstdint>

// ---------------------------------------------------------------------------
// GAT 2-layer model on MI355X.
// R8 post-mortem: spmm NOT byte-bound (halving bytes gave -5%); it is
//   latency-chain bound: only 4 row-loads in flight per group, flush branches
//   block pipelining.
// R9: node-parallel CSR spmm, 16-deep load burst per group (addresses via
//   shfl, loads into register array -> all 16 in flight), zero atomics,
//   dense row writes (self-loop guarantees coverage). post_kernel + accbuf
//   memsets deleted (bias+ELU fused into layer-1 spmm epilogue); layer 2
//   writes raw acc and keeps R7's proven post_pool. cdst deleted.
// ---------------------------------------------------------------------------

__device__ __forceinline__ float wave_reduce_sum(float v) {
#pragma unroll
  for (int off = 32; off > 0; off >>= 1) v += __shfl_xor(v, off, 64);
  return v;
}

__device__ __forceinline__ unsigned short f2bf(float f) {  // RNE
  unsigned int u = __float_as_uint(f);
  u += 0x7fffu + ((u >> 16) & 1u);
  return (unsigned short)(u >> 16);
}
__device__ __forceinline__ float bf2f(unsigned short u) {
  return __uint_as_float(((unsigned int)u) << 16);
}

// ---------------- CSR build ----------------

__global__ void deg_kernel(const int* __restrict__ ei, int E, int N,
                           int* __restrict__ deg) {
  int t = blockIdx.x * blockDim.x + threadIdx.x;
  int total = E + N;
  if (t >= total) return;
  int d = (t < E) ? ei[E + t] : (t - E);  // self loops appended
  atomicAdd(&deg[d], 1);
}

__global__ void scan1_kernel(const int* __restrict__ deg, int* __restrict__ rowptr,
                             int* __restrict__ partials, int n) {
  __shared__ int wsum[4];
  int t = threadIdx.x;
  int lane = t & 63, wv = t >> 6;
  int base = blockIdx.x * 2048 + t * 8;
  int v[8];
  int s = 0;
#pragma unroll
  for (int i = 0; i < 8; i++) {
    int idx = base + i;
    v[i] = (idx < n) ? deg[idx] : 0;
    s += v[i];
  }
  int x = s;
#pragma unroll
  for (int off = 1; off < 64; off <<= 1) {
    int u = __shfl_up(x, off, 64);
    if (lane >= off) x += u;
  }
  if (lane == 63) wsum[wv] = x;
  __syncthreads();
  int woff = 0;
  for (int j = 0; j < wv; j++) woff += wsum[j];
  int excl = woff + x - s;
#pragma unroll
  for (int i = 0; i < 8; i++) {
    int idx = base + i;
    if (idx < n) rowptr[idx] = excl;
    excl += v[i];
  }
  if (t == 255) partials[blockIdx.x] = woff + x;
}

__global__ void scan2_kernel(int* __restrict__ partials, int nb,
                             int* __restrict__ rowptr_end) {
  if (threadIdx.x == 0 && blockIdx.x == 0) {
    int run = 0;
    for (int i = 0; i < nb; i++) {
      int t = partials[i];
      partials[i] = run;
      run += t;
    }
    *rowptr_end = run;
  }
}

__global__ void scan3_kernel(int* __restrict__ rowptr, const int* __restrict__ partials,
                             int n) {
  int idx = blockIdx.x * blockDim.x + threadIdx.x;
  if (idx < n) rowptr[idx] += partials[idx >> 11];
}

__global__ void scatter_kernel(const int* __restrict__ ei, int E, int N,
                               int* __restrict__ cursor, int* __restrict__ csrc) {
  int t = blockIdx.x * blockDim.x + threadIdx.x;
  int total = E + N;
  if (t >= total) return;
  int s, d;
  if (t < E) {
    s = ei[t];
    d = ei[E + t];
  } else {
    s = d = t - E;
  }
  int pos = atomicAdd(&cursor[d], 1);
  csrc[pos] = s;
}

// gstart[g] = first node index with batch[node] >= g (batch sorted)
__global__ void bounds_kernel(const int* __restrict__ batch, int* __restrict__ gstart,
                              int N, int G) {
  int g = blockIdx.x * blockDim.x + threadIdx.x;
  if (g > G) return;
  int lo = 0, hi = N;
  while (lo < hi) {
    int mid = (lo + hi) >> 1;
    if (batch[mid] < g) lo = mid + 1;
    else hi = mid;
  }
  gstart[g] = lo;
}

// ---------------- dense compute ----------------

// hb[N][64] (bf16) = A[N][KDIM] @ W[KDIM][64]; fused al epilogue from the
// exact fp32 accumulators.
template <int KDIM>
__global__ __launch_bounds__(256) void gemm64(const float* __restrict__ A,
                                              const float* __restrict__ W,
                                              unsigned short* __restrict__ hb,
                                              const float* __restrict__ a_src,
                                              const float* __restrict__ a_dst,
                                              float* __restrict__ alsrc,
                                              float* __restrict__ aldst, int N) {
  __shared__ float As[32][68];
  __shared__ float Ws[32][68];
  const int block_m = blockIdx.x * 64;
  const int t = threadIdx.x;
  const int tc = t & 15;
  const int tr = t >> 4;
  const int c0 = tc * 4, r0 = tr * 4;
  float acc[4][4] = {};

  for (int kc = 0; kc < KDIM; kc += 32) {
    for (int q = t; q < 512; q += 256) {
      int node = q >> 3, f4 = q & 7;
      int gn = block_m + node;
      if (gn >= N) gn = N - 1;
      const float4 v = *(const float4*)(A + (size_t)gn * KDIM + kc + f4 * 4);
      As[f4 * 4 + 0][node] = v.x;
      As[f4 * 4 + 1][node] = v.y;
      As[f4 * 4 + 2][node] = v.z;
      As[f4 * 4 + 3][node] = v.w;
    }
    for (int q = t; q < 512; q += 256) {
      int k = q >> 4, f4 = q & 15;
      const float4 v = *(const float4*)(W + (size_t)(kc + k) * 64 + f4 * 4);
      *(float4*)&Ws[k][f4 * 4] = v;
    }
    __syncthreads();
#pragma unroll
    for (int k = 0; k < 32; ++k) {
      float4 a = *(const float4*)&As[k][r0];
      float4 b = *(const float4*)&Ws[k][c0];
      acc[0][0] += a.x * b.x; acc[0][1] += a.x * b.y; acc[0][2] += a.x * b.z; acc[0][3] += a.x * b.w;
      acc[1][0] += a.y * b.x; acc[1][1] += a.y * b.y; acc[1][2] += a.y * b.z; acc[1][3] += a.y * b.w;
      acc[2][0] += a.z * b.x; acc[2][1] += a.z * b.y; acc[2][2] += a.z * b.z; acc[2][3] += a.z * b.w;
      acc[3][0] += a.w * b.x; acc[3][1] += a.w * b.y; acc[3][2] += a.w * b.z; acc[3][3] += a.w * b.w;
    }
    __syncthreads();
  }

  const float as0 = a_src[c0], as1 = a_src[c0 + 1], as2 = a_src[c0 + 2], as3 = a_src[c0 + 3];
  const float ad0 = a_dst[c0], ad1 = a_dst[c0 + 1], ad2 = a_dst[c0 + 2], ad3 = a_dst[c0 + 3];
#pragma unroll
  for (int i = 0; i < 4; ++i) {
    int gn = block_m + r0 + i;
    if (gn < N) {
      ushort4 u;
      u.x = f2bf(acc[i][0]); u.y = f2bf(acc[i][1]);
      u.z = f2bf(acc[i][2]); u.w = f2bf(acc[i][3]);
      *(ushort4*)(hb + (size_t)gn * 64 + c0) = u;
    }
    float ps = acc[i][0] * as0 + acc[i][1] * as1 + acc[i][2] * as2 + acc[i][3] * as3;
    float pd = acc[i][0] * ad0 + acc[i][1] * ad1 + acc[i][2] * ad2 + acc[i][3] * ad3;
#pragma unroll
    for (int off = 1; off < 16; off <<= 1) {
      ps += __shfl_xor(ps, off, 64);
      pd += __shfl_xor(pd, off, 64);
    }
    if (tc == 0 && gn < N) {
      alsrc[gn] = ps;
      aldst[gn] = pd;
    }
  }
}

// 16 lanes per node: fused logit computation + segment softmax -> coef.
__global__ void coef_kernel(const int* __restrict__ rowptr, const int* __restrict__ csrc,
                            const float* __restrict__ alsrc, const float* __restrict__ aldst,
                            float* __restrict__ logit, float* __restrict__ coef, int N) {
  int tid = blockIdx.x * blockDim.x + threadIdx.x;
  int node = tid >> 4;
  int sub = tid & 15;
  if (node >= N) return;
  int start = rowptr[node];
  int end = rowptr[node + 1];
  float ad = aldst[node];

  float m = -1e30f;
  for (int i = start + sub; i < end; i += 16) {
    float e = alsrc[csrc[i]] + ad;
    e = (e > 0.f) ? e : 0.2f * e;  // leaky_relu 0.2
    logit[i] = e;
    m = fmaxf(m, e);
  }
#pragma unroll
  for (int off = 1; off < 16; off <<= 1) m = fmaxf(m, __shfl_xor(m, off, 64));

  float s = 0.f;
  for (int i = start + sub; i < end; i += 16) s += __expf(logit[i] - m);
#pragma unroll
  for (int off = 1; off < 16; off <<= 1) s += __shfl_xor(s, off, 64);

  float inv = 1.0f / s;  // >= 1 edge per node (self-loop)
  for (int i = start + sub; i < end; i += 16) coef[i] = __expf(logit[i] - m) * inv;
}

// Node-parallel CSR spmm: one 16-lane group per dst node, 16-deep row-load
// burst per chunk (all loads independent & hoistable), fp32 accumulate,
// dense row write (no atomics). ELU=1: fused bias+ELU epilogue (layer 1).
template <int ELU>
__global__ __launch_bounds__(256) void spmm_csr_kernel(
    const int* __restrict__ rowptr, const int* __restrict__ csrc,
    const float* __restrict__ coef, const unsigned short* __restrict__ hb,
    const float* __restrict__ bias, float* __restrict__ outbuf, int N) {
  const int t = threadIdx.x;
  const int l = t & 15;           // ushort4 slot within row
  const int gb = t & 48;          // group base lane within wave
  const int node = blockIdx.x * 16 + (t >> 4);
  if (node >= N) return;
  const int start = rowptr[node];
  const int end = rowptr[node + 1];

  float4 acc0 = make_float4(0.f, 0.f, 0.f, 0.f);
  float4 acc1 = make_float4(0.f, 0.f, 0.f, 0.f);
  float4 acc2 = make_float4(0.f, 0.f, 0.f, 0.f);
  float4 acc3 = make_float4(0.f, 0.f, 0.f, 0.f);

  for (int base = start; base < end; base += 16) {
    int i = base + l;
    bool valid = i < end;
    int s = valid ? csrc[i] : 0;      // coalesced 64B chunk load
    float c = valid ? coef[i] : 0.f;  // coalesced 64B chunk load

    ushort4 u[16];
    float cj[16];
#pragma unroll
    for (int j = 0; j < 16; ++j) {
      int sj = __shfl(s, gb + j, 64);
      cj[j] = __shfl(c, gb + j, 64);
      u[j] = *(const ushort4*)(hb + (size_t)sj * 64 + l * 4);  // 16 in flight
    }
#pragma unroll
    for (int j = 0; j < 16; ++j) {
      float4* A = ((j & 3) == 0) ? &acc0 : ((j & 3) == 1) ? &acc1
                : ((j & 3) == 2) ? &acc2 : &acc3;
      A->x += cj[j] * bf2f(u[j].x);
      A->y += cj[j] * bf2f(u[j].y);
      A->z += cj[j] * bf2f(u[j].z);
      A->w += cj[j] * bf2f(u[j].w);
    }
  }

  float4 r;
  r.x = (acc0.x + acc1.x) + (acc2.x + acc3.x);
  r.y = (acc0.y + acc1.y) + (acc2.y + acc3.y);
  r.z = (acc0.z + acc1.z) + (acc2.z + acc3.z);
  r.w = (acc0.w + acc1.w) + (acc2.w + acc3.w);
  if (ELU) {
    const float4 b4 = *(const float4*)(bias + l * 4);
    r.x += b4.x; r.y += b4.y; r.z += b4.z; r.w += b4.w;
    r.x = (r.x > 0.f) ? r.x : expm1f(r.x);
    r.y = (r.y > 0.f) ? r.y : expm1f(r.y);
    r.z = (r.z > 0.f) ? r.z : expm1f(r.z);
    r.w = (r.w > 0.f) ? r.w : expm1f(r.w);
  }
  *(float4*)(outbuf + (size_t)node * 64 + l * 4) = r;
}

// bias + ELU + hierarchical mean-pool accumulation (layer 2) — unchanged
// from R7 (proven past the post-timing determinism check).
__global__ __launch_bounds__(256) void post_pool_kernel(
    const float* __restrict__ acc, const float* __restrict__ bias,
    const int* __restrict__ batch, float* __restrict__ pool, int N) {
  __shared__ float4 red4[16][17];
  __shared__ int sB[16];
  __shared__ int uni;
  const int t = threadIdx.x;
  const int ln = t >> 4;
  const int f4 = t & 15;
  const int base = blockIdx.x * 16;
  const int node = base + ln;

  if (t < 16) {
    int nn = base + t;
    sB[t] = (nn < N) ? batch[nn] : -1;
  }
  __syncthreads();
  if (t == 0) {
    int u = (base + 15 < N);
    for (int i = 1; i < 16; i++) u &= (sB[i] == sB[0]);
    uni = u;
  }

  float4 v = make_float4(0.f, 0.f, 0.f, 0.f);
  if (node < N) {
    v = *(const float4*)(acc + ((size_t)node * 16 + f4) * 4);
    const float4 b4 = *(const float4*)(bias + f4 * 4);
    v.x += b4.x; v.y += b4.y; v.z += b4.z; v.w += b4.w;
    v.x = (v.x > 0.f) ? v.x : expm1f(v.x);
    v.y = (v.y > 0.f) ? v.y : expm1f(v.y);
    v.z = (v.z > 0.f) ? v.z : expm1f(v.z);
    v.w = (v.w > 0.f) ? v.w : expm1f(v.w);
  }
  red4[ln][f4] = v;
  __syncthreads();

  if (t < 64) {
    const float* rf = (const float*)red4;  // row stride 68 floats
    if (uni) {
      float s = 0.f;
#pragma unroll
      for (int n = 0; n < 16; n++) s += rf[n * 68 + t];
      atomicAdd(&pool[(size_t)sB[0] * 64 + t], s);
    } else {
      for (int n = 0; n < 16; n++) {
        int g = sB[n];
        if (g >= 0) atomicAdd(&pool[(size_t)g * 64 + t], rf[n * 68 + t]);
      }
    }
  }
}

// out[g] = (pool[g,:]/cnt[g]) . Wfc + bfc ; cnt from sorted-batch bounds.
__global__ void final_kernel(const float* __restrict__ pool, const int* __restrict__ gstart,
                             const float* __restrict__ Wfc, const float* __restrict__ bfc,
                             float* __restrict__ out, int G) {
  int wid = (blockIdx.x * blockDim.x + threadIdx.x) >> 6;
  int lane = threadIdx.x & 63;
  if (wid >= G) return;
  float c = (float)max(gstart[wid + 1] - gstart[wid], 1);
  float v = pool[(size_t)wid * 64 + lane] * (1.0f / c) * Wfc[lane];
  v = wave_reduce_sum(v);
  if (lane == 0) out[wid] = v + bfc[0];
}

// ---------------------------------------------------------------------------

extern "C" void kernel_launch(void* const* d_in, const int* in_sizes, int n_in,
                              void* d_out, int out_size, void* d_ws, size_t ws_size,
                              hipStream_t stream) {
  const float* x     = (const float*)d_in[0];
  const int*   ei    = (const int*)d_in[1];
  const int*   batch = (const int*)d_in[2];
  const float* W1    = (const float*)d_in[3];
  const float* asrc1 = (const float*)d_in[4];
  const float* adst1 = (const float*)d_in[5];
  const float* b1    = (const float*)d_in[6];
  const float* W2    = (const float*)d_in[7];
  const float* asrc2 = (const float*)d_in[8];
  const float* adst2 = (const float*)d_in[9];
  const float* b2    = (const float*)d_in[10];
  const float* Wfc   = (const float*)d_in[11];
  const float* bfc   = (const float*)d_in[12];
  float* out = (float*)d_out;

  const int N = in_sizes[0] / 128;  // 100000
  const int E = in_sizes[1] / 2;    // 1600000
  const int G = 256;
  const int M = E + N;              // edges incl self-loops

  // workspace carve (256B aligned)
  char* p = (char*)d_ws;
  auto alloc = [&](size_t bytes) {
    char* r = p;
    p += (bytes + 255) & ~size_t(255);
    return r;
  };
  float*          h1e    = (float*)alloc((size_t)N * 64 * 4);
  float*          accbuf = (float*)alloc((size_t)N * 64 * 4);
  unsigned short* hb     = (unsigned short*)alloc((size_t)N * 64 * 2);
  float* alsrc  = (float*)alloc((size_t)N * 4);
  float* aldst  = (float*)alloc((size_t)N * 4);
  int*   deg    = (int*)alloc((size_t)N * 4);
  int*   rowptr = (int*)alloc((size_t)(N + 1) * 4);
  int*   cursor = (int*)alloc((size_t)N * 4);
  int*   csrc   = (int*)alloc((size_t)M * 4);
  float* logit  = (float*)alloc((size_t)M * 4);
  float* coef   = (float*)alloc((size_t)M * 4);
  float* pool   = (float*)alloc((size_t)G * 64 * 4);
  int*   gstart = (int*)alloc((size_t)(G + 1) * 4);
  int*   partials = (int*)alloc(256 * 4);

  // ---- CSR build + graph bounds (shared by both layers) ----
  hipMemsetAsync(deg, 0, (size_t)N * 4, stream);
  deg_kernel<<<(M + 255) / 256, 256, 0, stream>>>(ei, E, N, deg);
  int nb = (N + 2047) / 2048;
  scan1_kernel<<<nb, 256, 0, stream>>>(deg, rowptr, partials, N);
  scan2_kernel<<<1, 64, 0, stream>>>(partials, nb, rowptr + N);
  scan3_kernel<<<(N + 255) / 256, 256, 0, stream>>>(rowptr, partials, N);
  hipMemcpyAsync(cursor, rowptr, (size_t)N * 4, hipMemcpyDeviceToDevice, stream);
  scatter_kernel<<<(M + 255) / 256, 256, 0, stream>>>(ei, E, N, cursor, csrc);
  bounds_kernel<<<2, 256, 0, stream>>>(batch, gstart, N, G);

  // ---- layer 1 ----
  gemm64<128><<<(N + 63) / 64, 256, 0, stream>>>(x, W1, hb, asrc1, adst1, alsrc, aldst, N);
  coef_kernel<<<(N * 16 + 255) / 256, 256, 0, stream>>>(rowptr, csrc, alsrc, aldst, logit, coef, N);
  spmm_csr_kernel<1><<<(N + 15) / 16, 256, 0, stream>>>(rowptr, csrc, coef, hb, b1, h1e, N);

  // ---- layer 2 ----
  gemm64<64><<<(N + 63) / 64, 256, 0, stream>>>(h1e, W2, hb, asrc2, adst2, alsrc, aldst, N);
  coef_kernel<<<(N * 16 + 255) / 256, 256, 0, stream>>>(rowptr, csrc, alsrc, aldst, logit, coef, N);
  spmm_csr_kernel<0><<<(N + 15) / 16, 256, 0, stream>>>(rowptr, csrc, coef, hb, nullptr, accbuf, N);
  hipMemsetAsync(pool, 0, (size_t)G * 64 * 4, stream);
  post_pool_kernel<<<(N + 15) / 16, 256, 0, stream>>>(accbuf, b2, batch, pool, N);

  // ---- readout ----
  final_kernel<<<(G * 64 + 255) / 256, 256, 0, stream>>>(pool, gstart, Wfc, bfc, out, G);
}

// Round 10
// 338.854 us; speedup vs baseline: 3.7414x; 1.3983x over previous
//
#include <hip/hip_runtime.h>
#include <hip/hip_bf16.h>
#include <cstdint>

// ---------------------------------------------------------------------------
// GAT 2-layer model on MI355X.
// R9 post-mortem: scatter_kernel 130us — WRITE_SIZE 108MB for a 6.8MB csrc:
//   random 4B stores dirty whole 64B lines (~16x writeback amplification);
//   effective ceiling ~0.9 TB/s for scattered partial-line writebacks.
// R10: locality-aware CSR build replaces deg/scan/scatter entirely:
//   bin_count (391 bins x 256 dst nodes) -> bin_scan (bases = CSR offsets)
//   -> bin_place (per-block contiguous runs per bin, ~1.3x amplification)
//   -> csr_finalize (per-bin rowptr + csrc scatter confined to a 17KB
//   window -> full-line writebacks). Downstream unchanged from R9.
// ---------------------------------------------------------------------------

#define BIN_SHIFT 8
#define BIN_NODES 256
#define PLACE_CHUNK 8192

__device__ __forceinline__ float wave_reduce_sum(float v) {
#pragma unroll
  for (int off = 32; off > 0; off >>= 1) v += __shfl_xor(v, off, 64);
  return v;
}

__device__ __forceinline__ unsigned short f2bf(float f) {  // RNE
  unsigned int u = __float_as_uint(f);
  u += 0x7fffu + ((u >> 16) & 1u);
  return (unsigned short)(u >> 16);
}
__device__ __forceinline__ float bf2f(unsigned short u) {
  return __uint_as_float(((unsigned int)u) << 16);
}

// ---------------- CSR build (binned, low write-amplification) ----------------

// K1: global bin histogram. Edge t<E: (src=ei[t], dst=ei[E+t]); t>=E: self-loop.
__global__ void bin_count_kernel(const int* __restrict__ ei, int E, int M, int NB,
                                 int* __restrict__ binCnt) {
  extern __shared__ int hist[];
  for (int i = threadIdx.x; i < NB; i += blockDim.x) hist[i] = 0;
  __syncthreads();
  int stride = gridDim.x * blockDim.x;
  for (int t = blockIdx.x * blockDim.x + threadIdx.x; t < M; t += stride) {
    int d = (t < E) ? ei[E + t] : (t - E);
    atomicAdd(&hist[d >> BIN_SHIFT], 1);
  }
  __syncthreads();
  for (int i = threadIdx.x; i < NB; i += blockDim.x)
    if (hist[i]) atomicAdd(&binCnt[i], hist[i]);
}

// K2: exclusive scan of binCnt -> binBase (and init binCursor). 64 threads.
__global__ void bin_scan_kernel(const int* __restrict__ binCnt, int NB,
                                int* __restrict__ binBase, int* __restrict__ binCursor) {
  int lane = threadIdx.x;  // 0..63
  int per = (NB + 63) / 64;  // <= 8 for N<=131072
  int vals[8];
  int base = lane * per;
  int s = 0;
#pragma unroll
  for (int i = 0; i < 8; i++) {
    int idx = base + i;
    int v = (i < per && idx < NB) ? binCnt[idx] : 0;
    vals[i] = v;
    s += v;
  }
  int x = s;
#pragma unroll
  for (int off = 1; off < 64; off <<= 1) {
    int u = __shfl_up(x, off, 64);
    if (lane >= off) x += u;
  }
  int excl = x - s;
#pragma unroll
  for (int i = 0; i < 8; i++) {
    int idx = base + i;
    if (i < per && idx < NB) {
      binBase[idx] = excl;
      binCursor[idx] = excl;
    }
    excl += vals[i];
  }
  if (lane == 63) binBase[NB] = x;  // == M
}

// K3: place edges into bin-major staging. Per-block LDS histogram -> one
// global reservation per (block,bin) -> contiguous per-bin runs.
__global__ __launch_bounds__(256) void bin_place_kernel(
    const int* __restrict__ ei, int E, int M, int NB,
    int* __restrict__ binCursor, int2* __restrict__ binned) {
  extern __shared__ int sh[];
  int* res = sh;       // [NB] reserved global base per bin
  int* cur = sh + NB;  // [NB] hist / local cursor
  const int t = threadIdx.x;
  const int cbase = blockIdx.x * PLACE_CHUNK;
  const int cend = min(cbase + PLACE_CHUNK, M);

  for (int i = t; i < NB; i += 256) cur[i] = 0;
  __syncthreads();
  for (int i = cbase + t; i < cend; i += 256) {
    int d = (i < E) ? ei[E + i] : (i - E);
    atomicAdd(&cur[d >> BIN_SHIFT], 1);
  }
  __syncthreads();
  for (int i = t; i < NB; i += 256) {
    int c = cur[i];
    res[i] = c ? atomicAdd(&binCursor[i], c) : 0;
  }
  __syncthreads();
  for (int i = t; i < NB; i += 256) cur[i] = 0;
  __syncthreads();
  for (int i = cbase + t; i < cend; i += 256) {
    int s, d;
    if (i < E) { s = ei[i]; d = ei[E + i]; } else { s = d = i - E; }
    int b = d >> BIN_SHIFT;
    int r = atomicAdd(&cur[b], 1);
    binned[res[b] + r] = make_int2(s, d);
  }
}

// K4: per-bin rowptr + csrc finalize. Block b owns bin b (256 nodes, edges
// [binBase[b], binBase[b+1])). All csrc writes land in the bin's own window.
__global__ __launch_bounds__(256) void csr_finalize_kernel(
    const int2* __restrict__ binned, const int* __restrict__ binBase,
    int* __restrict__ rowptr, int* __restrict__ csrc, int N, int NB, int M) {
  __shared__ int cnt[256];
  __shared__ int off[256];
  __shared__ int wsum[4];
  const int b = blockIdx.x;
  const int t = threadIdx.x;
  const int nodeBase = b << BIN_SHIFT;
  const int eStart = binBase[b], eEnd = binBase[b + 1];

  cnt[t] = 0;
  __syncthreads();
  for (int i = eStart + t; i < eEnd; i += 256) {
    atomicAdd(&cnt[binned[i].y - nodeBase], 1);
  }
  __syncthreads();
  {  // exclusive scan cnt -> off
    int lane = t & 63, wv = t >> 6;
    int v = cnt[t];
    int x = v;
#pragma unroll
    for (int o = 1; o < 64; o <<= 1) {
      int u = __shfl_up(x, o, 64);
      if (lane >= o) x += u;
    }
    if (lane == 63) wsum[wv] = x;
    __syncthreads();
    int woff = 0;
    for (int j = 0; j < wv; j++) woff += wsum[j];
    off[t] = woff + x - v;
  }
  __syncthreads();
  int node = nodeBase + t;
  if (node < N) rowptr[node] = eStart + off[t];
  if (b == NB - 1 && t == 0) rowptr[N] = M;
  cnt[t] = off[t];  // reuse as cursor
  __syncthreads();
  for (int i = eStart + t; i < eEnd; i += 256) {
    int2 e = binned[i];
    int r = atomicAdd(&cnt[e.y - nodeBase], 1);
    csrc[eStart + r] = e.x;
  }
}

// gstart[g] = first node index with batch[node] >= g (batch sorted)
__global__ void bounds_kernel(const int* __restrict__ batch, int* __restrict__ gstart,
                              int N, int G) {
  int g = blockIdx.x * blockDim.x + threadIdx.x;
  if (g > G) return;
  int lo = 0, hi = N;
  while (lo < hi) {
    int mid = (lo + hi) >> 1;
    if (batch[mid] < g) lo = mid + 1;
    else hi = mid;
  }
  gstart[g] = lo;
}

// ---------------- dense compute ----------------

// hb[N][64] (bf16) = A[N][KDIM] @ W[KDIM][64]; fused al epilogue from the
// exact fp32 accumulators.
template <int KDIM>
__global__ __launch_bounds__(256) void gemm64(const float* __restrict__ A,
                                              const float* __restrict__ W,
                                              unsigned short* __restrict__ hb,
                                              const float* __restrict__ a_src,
                                              const float* __restrict__ a_dst,
                                              float* __restrict__ alsrc,
                                              float* __restrict__ aldst, int N) {
  __shared__ float As[32][68];
  __shared__ float Ws[32][68];
  const int block_m = blockIdx.x * 64;
  const int t = threadIdx.x;
  const int tc = t & 15;
  const int tr = t >> 4;
  const int c0 = tc * 4, r0 = tr * 4;
  float acc[4][4] = {};

  for (int kc = 0; kc < KDIM; kc += 32) {
    for (int q = t; q < 512; q += 256) {
      int node = q >> 3, f4 = q & 7;
      int gn = block_m + node;
      if (gn >= N) gn = N - 1;
      const float4 v = *(const float4*)(A + (size_t)gn * KDIM + kc + f4 * 4);
      As[f4 * 4 + 0][node] = v.x;
      As[f4 * 4 + 1][node] = v.y;
      As[f4 * 4 + 2][node] = v.z;
      As[f4 * 4 + 3][node] = v.w;
    }
    for (int q = t; q < 512; q += 256) {
      int k = q >> 4, f4 = q & 15;
      const float4 v = *(const float4*)(W + (size_t)(kc + k) * 64 + f4 * 4);
      *(float4*)&Ws[k][f4 * 4] = v;
    }
    __syncthreads();
#pragma unroll
    for (int k = 0; k < 32; ++k) {
      float4 a = *(const float4*)&As[k][r0];
      float4 b = *(const float4*)&Ws[k][c0];
      acc[0][0] += a.x * b.x; acc[0][1] += a.x * b.y; acc[0][2] += a.x * b.z; acc[0][3] += a.x * b.w;
      acc[1][0] += a.y * b.x; acc[1][1] += a.y * b.y; acc[1][2] += a.y * b.z; acc[1][3] += a.y * b.w;
      acc[2][0] += a.z * b.x; acc[2][1] += a.z * b.y; acc[2][2] += a.z * b.z; acc[2][3] += a.z * b.w;
      acc[3][0] += a.w * b.x; acc[3][1] += a.w * b.y; acc[3][2] += a.w * b.z; acc[3][3] += a.w * b.w;
    }
    __syncthreads();
  }

  const float as0 = a_src[c0], as1 = a_src[c0 + 1], as2 = a_src[c0 + 2], as3 = a_src[c0 + 3];
  const float ad0 = a_dst[c0], ad1 = a_dst[c0 + 1], ad2 = a_dst[c0 + 2], ad3 = a_dst[c0 + 3];
#pragma unroll
  for (int i = 0; i < 4; ++i) {
    int gn = block_m + r0 + i;
    if (gn < N) {
      ushort4 u;
      u.x = f2bf(acc[i][0]); u.y = f2bf(acc[i][1]);
      u.z = f2bf(acc[i][2]); u.w = f2bf(acc[i][3]);
      *(ushort4*)(hb + (size_t)gn * 64 + c0) = u;
    }
    float ps = acc[i][0] * as0 + acc[i][1] * as1 + acc[i][2] * as2 + acc[i][3] * as3;
    float pd = acc[i][0] * ad0 + acc[i][1] * ad1 + acc[i][2] * ad2 + acc[i][3] * ad3;
#pragma unroll
    for (int off = 1; off < 16; off <<= 1) {
      ps += __shfl_xor(ps, off, 64);
      pd += __shfl_xor(pd, off, 64);
    }
    if (tc == 0 && gn < N) {
      alsrc[gn] = ps;
      aldst[gn] = pd;
    }
  }
}

// 16 lanes per node: fused logit computation + segment softmax -> coef.
__global__ void coef_kernel(const int* __restrict__ rowptr, const int* __restrict__ csrc,
                            const float* __restrict__ alsrc, const float* __restrict__ aldst,
                            float* __restrict__ logit, float* __restrict__ coef, int N) {
  int tid = blockIdx.x * blockDim.x + threadIdx.x;
  int node = tid >> 4;
  int sub = tid & 15;
  if (node >= N) return;
  int start = rowptr[node];
  int end = rowptr[node + 1];
  float ad = aldst[node];

  float m = -1e30f;
  for (int i = start + sub; i < end; i += 16) {
    float e = alsrc[csrc[i]] + ad;
    e = (e > 0.f) ? e : 0.2f * e;  // leaky_relu 0.2
    logit[i] = e;
    m = fmaxf(m, e);
  }
#pragma unroll
  for (int off = 1; off < 16; off <<= 1) m = fmaxf(m, __shfl_xor(m, off, 64));

  float s = 0.f;
  for (int i = start + sub; i < end; i += 16) s += __expf(logit[i] - m);
#pragma unroll
  for (int off = 1; off < 16; off <<= 1) s += __shfl_xor(s, off, 64);

  float inv = 1.0f / s;  // >= 1 edge per node (self-loop)
  for (int i = start + sub; i < end; i += 16) coef[i] = __expf(logit[i] - m) * inv;
}

// Node-parallel CSR spmm: one 16-lane group per dst node, 16-deep row-load
// burst per chunk, fp32 accumulate, dense row write (no atomics).
template <int ELU>
__global__ __launch_bounds__(256) void spmm_csr_kernel(
    const int* __restrict__ rowptr, const int* __restrict__ csrc,
    const float* __restrict__ coef, const unsigned short* __restrict__ hb,
    const float* __restrict__ bias, float* __restrict__ outbuf, int N) {
  const int t = threadIdx.x;
  const int l = t & 15;
  const int gb = t & 48;
  const int node = blockIdx.x * 16 + (t >> 4);
  if (node >= N) return;
  const int start = rowptr[node];
  const int end = rowptr[node + 1];

  float4 acc0 = make_float4(0.f, 0.f, 0.f, 0.f);
  float4 acc1 = make_float4(0.f, 0.f, 0.f, 0.f);
  float4 acc2 = make_float4(0.f, 0.f, 0.f, 0.f);
  float4 acc3 = make_float4(0.f, 0.f, 0.f, 0.f);

  for (int base = start; base < end; base += 16) {
    int i = base + l;
    bool valid = i < end;
    int s = valid ? csrc[i] : 0;
    float c = valid ? coef[i] : 0.f;

    ushort4 u[16];
    float cj[16];
#pragma unroll
    for (int j = 0; j < 16; ++j) {
      int sj = __shfl(s, gb + j, 64);
      cj[j] = __shfl(c, gb + j, 64);
      u[j] = *(const ushort4*)(hb + (size_t)sj * 64 + l * 4);
    }
#pragma unroll
    for (int j = 0; j < 16; ++j) {
      float4* A = ((j & 3) == 0) ? &acc0 : ((j & 3) == 1) ? &acc1
                : ((j & 3) == 2) ? &acc2 : &acc3;
      A->x += cj[j] * bf2f(u[j].x);
      A->y += cj[j] * bf2f(u[j].y);
      A->z += cj[j] * bf2f(u[j].z);
      A->w += cj[j] * bf2f(u[j].w);
    }
  }

  float4 r;
  r.x = (acc0.x + acc1.x) + (acc2.x + acc3.x);
  r.y = (acc0.y + acc1.y) + (acc2.y + acc3.y);
  r.z = (acc0.z + acc1.z) + (acc2.z + acc3.z);
  r.w = (acc0.w + acc1.w) + (acc2.w + acc3.w);
  if (ELU) {
    const float4 b4 = *(const float4*)(bias + l * 4);
    r.x += b4.x; r.y += b4.y; r.z += b4.z; r.w += b4.w;
    r.x = (r.x > 0.f) ? r.x : expm1f(r.x);
    r.y = (r.y > 0.f) ? r.y : expm1f(r.y);
    r.z = (r.z > 0.f) ? r.z : expm1f(r.z);
    r.w = (r.w > 0.f) ? r.w : expm1f(r.w);
  }
  *(float4*)(outbuf + (size_t)node * 64 + l * 4) = r;
}

// bias + ELU + hierarchical mean-pool accumulation (layer 2) — unchanged.
__global__ __launch_bounds__(256) void post_pool_kernel(
    const float* __restrict__ acc, const float* __restrict__ bias,
    const int* __restrict__ batch, float* __restrict__ pool, int N) {
  __shared__ float4 red4[16][17];
  __shared__ int sB[16];
  __shared__ int uni;
  const int t = threadIdx.x;
  const int ln = t >> 4;
  const int f4 = t & 15;
  const int base = blockIdx.x * 16;
  const int node = base + ln;

  if (t < 16) {
    int nn = base + t;
    sB[t] = (nn < N) ? batch[nn] : -1;
  }
  __syncthreads();
  if (t == 0) {
    int u = (base + 15 < N);
    for (int i = 1; i < 16; i++) u &= (sB[i] == sB[0]);
    uni = u;
  }

  float4 v = make_float4(0.f, 0.f, 0.f, 0.f);
  if (node < N) {
    v = *(const float4*)(acc + ((size_t)node * 16 + f4) * 4);
    const float4 b4 = *(const float4*)(bias + f4 * 4);
    v.x += b4.x; v.y += b4.y; v.z += b4.z; v.w += b4.w;
    v.x = (v.x > 0.f) ? v.x : expm1f(v.x);
    v.y = (v.y > 0.f) ? v.y : expm1f(v.y);
    v.z = (v.z > 0.f) ? v.z : expm1f(v.z);
    v.w = (v.w > 0.f) ? v.w : expm1f(v.w);
  }
  red4[ln][f4] = v;
  __syncthreads();

  if (t < 64) {
    const float* rf = (const float*)red4;  // row stride 68 floats
    if (uni) {
      float s = 0.f;
#pragma unroll
      for (int n = 0; n < 16; n++) s += rf[n * 68 + t];
      atomicAdd(&pool[(size_t)sB[0] * 64 + t], s);
    } else {
      for (int n = 0; n < 16; n++) {
        int g = sB[n];
        if (g >= 0) atomicAdd(&pool[(size_t)g * 64 + t], rf[n * 68 + t]);
      }
    }
  }
}

// out[g] = (pool[g,:]/cnt[g]) . Wfc + bfc ; cnt from sorted-batch bounds.
__global__ void final_kernel(const float* __restrict__ pool, const int* __restrict__ gstart,
                             const float* __restrict__ Wfc, const float* __restrict__ bfc,
                             float* __restrict__ out, int G) {
  int wid = (blockIdx.x * blockDim.x + threadIdx.x) >> 6;
  int lane = threadIdx.x & 63;
  if (wid >= G) return;
  float c = (float)max(gstart[wid + 1] - gstart[wid], 1);
  float v = pool[(size_t)wid * 64 + lane] * (1.0f / c) * Wfc[lane];
  v = wave_reduce_sum(v);
  if (lane == 0) out[wid] = v + bfc[0];
}

// ---------------------------------------------------------------------------

extern "C" void kernel_launch(void* const* d_in, const int* in_sizes, int n_in,
                              void* d_out, int out_size, void* d_ws, size_t ws_size,
                              hipStream_t stream) {
  const float* x     = (const float*)d_in[0];
  const int*   ei    = (const int*)d_in[1];
  const int*   batch = (const int*)d_in[2];
  const float* W1    = (const float*)d_in[3];
  const float* asrc1 = (const float*)d_in[4];
  const float* adst1 = (const float*)d_in[5];
  const float* b1    = (const float*)d_in[6];
  const float* W2    = (const float*)d_in[7];
  const float* asrc2 = (const float*)d_in[8];
  const float* adst2 = (const float*)d_in[9];
  const float* b2    = (const float*)d_in[10];
  const float* Wfc   = (const float*)d_in[11];
  const float* bfc   = (const float*)d_in[12];
  float* out = (float*)d_out;

  const int N = in_sizes[0] / 128;  // 100000
  const int E = in_sizes[1] / 2;    // 1600000
  const int G = 256;
  const int M = E + N;              // edges incl self-loops
  const int NB = (N + BIN_NODES - 1) >> BIN_SHIFT;  // 391 bins

  // workspace carve (256B aligned)
  char* p = (char*)d_ws;
  auto alloc = [&](size_t bytes) {
    char* r = p;
    p += (bytes + 255) & ~size_t(255);
    return r;
  };
  float*          h1e    = (float*)alloc((size_t)N * 64 * 4);
  float*          accbuf = (float*)alloc((size_t)N * 64 * 4);
  unsigned short* hb     = (unsigned short*)alloc((size_t)N * 64 * 2);
  float* alsrc  = (float*)alloc((size_t)N * 4);
  float* aldst  = (float*)alloc((size_t)N * 4);
  int*   rowptr = (int*)alloc((size_t)(N + 1) * 4);
  int*   csrc   = (int*)alloc((size_t)M * 4);
  int2*  binned = (int2*)alloc((size_t)M * 8);
  int*   binCnt = (int*)alloc((size_t)NB * 4);
  int*   binBase = (int*)alloc((size_t)(NB + 1) * 4);
  int*   binCursor = (int*)alloc((size_t)NB * 4);
  float* logit  = (float*)alloc((size_t)M * 4);
  float* coef   = (float*)alloc((size_t)M * 4);
  float* pool   = (float*)alloc((size_t)G * 64 * 4);
  int*   gstart = (int*)alloc((size_t)(G + 1) * 4);

  // ---- CSR build (binned) + graph bounds ----
  hipMemsetAsync(binCnt, 0, (size_t)NB * 4, stream);
  bin_count_kernel<<<512, 256, NB * 4, stream>>>(ei, E, M, NB, binCnt);
  bin_scan_kernel<<<1, 64, 0, stream>>>(binCnt, NB, binBase, binCursor);
  bin_place_kernel<<<(M + PLACE_CHUNK - 1) / PLACE_CHUNK, 256, 2 * NB * 4, stream>>>(
      ei, E, M, NB, binCursor, binned);
  csr_finalize_kernel<<<NB, 256, 0, stream>>>(binned, binBase, rowptr, csrc, N, NB, M);
  bounds_kernel<<<2, 256, 0, stream>>>(batch, gstart, N, G);

  // ---- layer 1 ----
  gemm64<128><<<(N + 63) / 64, 256, 0, stream>>>(x, W1, hb, asrc1, adst1, alsrc, aldst, N);
  coef_kernel<<<(N * 16 + 255) / 256, 256, 0, stream>>>(rowptr, csrc, alsrc, aldst, logit, coef, N);
  spmm_csr_kernel<1><<<(N + 15) / 16, 256, 0, stream>>>(rowptr, csrc, coef, hb, b1, h1e, N);

  // ---- layer 2 ----
  gemm64<64><<<(N + 63) / 64, 256, 0, stream>>>(h1e, W2, hb, asrc2, adst2, alsrc, aldst, N);
  coef_kernel<<<(N * 16 + 255) / 256, 256, 0, stream>>>(rowptr, csrc, alsrc, aldst, logit, coef, N);
  spmm_csr_kernel<0><<<(N + 15) / 16, 256, 0, stream>>>(rowptr, csrc, coef, hb, nullptr, accbuf, N);
  hipMemsetAsync(pool, 0, (size_t)G * 64 * 4, stream);
  post_pool_kernel<<<(N + 15) / 16, 256, 0, stream>>>(accbuf, b2, batch, pool, N);

  // ---- readout ----
  final_kernel<<<(G * 64 + 255) / 256, 256, 0, stream>>>(pool, gstart, Wfc, bfc, out, G);
}

// Round 11
// 311.587 us; speedup vs baseline: 4.0688x; 1.0875x over previous
//
#include <hip/hip_runtime.h>
#include <hip/hip_bf16.h>
#include <cstdint>

// ---------------------------------------------------------------------------
// GAT 2-layer model on MI355X.
// R10: binned CSR build fixed the scatter write-amplification (474->339us).
// R11: softmax fused INTO spmm via online softmax. Unlike R1 (which died on
//   serial softmax phases draining the memory pipe), here the 16-deep row
//   burst depends only on csrc -> row loads issue first and their latency
//   covers the alsrc-gather/exp/shuffle chain. Deletes coef_kernel x2, the
//   logit/coef arrays (~27MB/layer traffic), 2 launches. Normalization is a
//   single acc/ssum at the end (deterministic chunk order).
//   bin_scan + bounds merged into one launch.
// ---------------------------------------------------------------------------

#define BIN_SHIFT 8
#define BIN_NODES 256
#define PLACE_CHUNK 8192

__device__ __forceinline__ float wave_reduce_sum(float v) {
#pragma unroll
  for (int off = 32; off > 0; off >>= 1) v += __shfl_xor(v, off, 64);
  return v;
}

__device__ __forceinline__ unsigned short f2bf(float f) {  // RNE
  unsigned int u = __float_as_uint(f);
  u += 0x7fffu + ((u >> 16) & 1u);
  return (unsigned short)(u >> 16);
}
__device__ __forceinline__ float bf2f(unsigned short u) {
  return __uint_as_float(((unsigned int)u) << 16);
}

// ---------------- CSR build (binned, low write-amplification) ----------------

__global__ void bin_count_kernel(const int* __restrict__ ei, int E, int M, int NB,
                                 int* __restrict__ binCnt) {
  extern __shared__ int hist[];
  for (int i = threadIdx.x; i < NB; i += blockDim.x) hist[i] = 0;
  __syncthreads();
  int stride = gridDim.x * blockDim.x;
  for (int t = blockIdx.x * blockDim.x + threadIdx.x; t < M; t += stride) {
    int d = (t < E) ? ei[E + t] : (t - E);
    atomicAdd(&hist[d >> BIN_SHIFT], 1);
  }
  __syncthreads();
  for (int i = threadIdx.x; i < NB; i += blockDim.x)
    if (hist[i]) atomicAdd(&binCnt[i], hist[i]);
}

// block 0: exclusive scan of binCnt -> binBase/binCursor (64 lanes).
// blocks 1..2: gstart[g] = lower_bound(batch, g) (batch sorted).
__global__ void scan_bounds_kernel(const int* __restrict__ binCnt, int NB,
                                   int* __restrict__ binBase, int* __restrict__ binCursor,
                                   const int* __restrict__ batch, int* __restrict__ gstart,
                                   int N, int G) {
  if (blockIdx.x == 0) {
    int lane = threadIdx.x;
    if (lane >= 64) return;
    int per = (NB + 63) / 64;  // <= 8
    int vals[8];
    int base = lane * per;
    int s = 0;
#pragma unroll
    for (int i = 0; i < 8; i++) {
      int idx = base + i;
      int v = (i < per && idx < NB) ? binCnt[idx] : 0;
      vals[i] = v;
      s += v;
    }
    int x = s;
#pragma unroll
    for (int off = 1; off < 64; off <<= 1) {
      int u = __shfl_up(x, off, 64);
      if (lane >= off) x += u;
    }
    int excl = x - s;
#pragma unroll
    for (int i = 0; i < 8; i++) {
      int idx = base + i;
      if (i < per && idx < NB) {
        binBase[idx] = excl;
        binCursor[idx] = excl;
      }
      excl += vals[i];
    }
    if (lane == 63) binBase[NB] = x;  // == M
  } else {
    int g = (blockIdx.x - 1) * 256 + threadIdx.x;
    if (g > G) return;
    int lo = 0, hi = N;
    while (lo < hi) {
      int mid = (lo + hi) >> 1;
      if (batch[mid] < g) lo = mid + 1;
      else hi = mid;
    }
    gstart[g] = lo;
  }
}

__global__ __launch_bounds__(256) void bin_place_kernel(
    const int* __restrict__ ei, int E, int M, int NB,
    int* __restrict__ binCursor, int2* __restrict__ binned) {
  extern __shared__ int sh[];
  int* res = sh;       // [NB]
  int* cur = sh + NB;  // [NB]
  const int t = threadIdx.x;
  const int cbase = blockIdx.x * PLACE_CHUNK;
  const int cend = min(cbase + PLACE_CHUNK, M);

  for (int i = t; i < NB; i += 256) cur[i] = 0;
  __syncthreads();
  for (int i = cbase + t; i < cend; i += 256) {
    int d = (i < E) ? ei[E + i] : (i - E);
    atomicAdd(&cur[d >> BIN_SHIFT], 1);
  }
  __syncthreads();
  for (int i = t; i < NB; i += 256) {
    int c = cur[i];
    res[i] = c ? atomicAdd(&binCursor[i], c) : 0;
  }
  __syncthreads();
  for (int i = t; i < NB; i += 256) cur[i] = 0;
  __syncthreads();
  for (int i = cbase + t; i < cend; i += 256) {
    int s, d;
    if (i < E) { s = ei[i]; d = ei[E + i]; } else { s = d = i - E; }
    int b = d >> BIN_SHIFT;
    int r = atomicAdd(&cur[b], 1);
    binned[res[b] + r] = make_int2(s, d);
  }
}

__global__ __launch_bounds__(256) void csr_finalize_kernel(
    const int2* __restrict__ binned, const int* __restrict__ binBase,
    int* __restrict__ rowptr, int* __restrict__ csrc, int N, int NB, int M) {
  __shared__ int cnt[256];
  __shared__ int off[256];
  __shared__ int wsum[4];
  const int b = blockIdx.x;
  const int t = threadIdx.x;
  const int nodeBase = b << BIN_SHIFT;
  const int eStart = binBase[b], eEnd = binBase[b + 1];

  cnt[t] = 0;
  __syncthreads();
  for (int i = eStart + t; i < eEnd; i += 256) {
    atomicAdd(&cnt[binned[i].y - nodeBase], 1);
  }
  __syncthreads();
  {
    int lane = t & 63, wv = t >> 6;
    int v = cnt[t];
    int x = v;
#pragma unroll
    for (int o = 1; o < 64; o <<= 1) {
      int u = __shfl_up(x, o, 64);
      if (lane >= o) x += u;
    }
    if (lane == 63) wsum[wv] = x;
    __syncthreads();
    int woff = 0;
    for (int j = 0; j < wv; j++) woff += wsum[j];
    off[t] = woff + x - v;
  }
  __syncthreads();
  int node = nodeBase + t;
  if (node < N) rowptr[node] = eStart + off[t];
  if (b == NB - 1 && t == 0) rowptr[N] = M;
  cnt[t] = off[t];
  __syncthreads();
  for (int i = eStart + t; i < eEnd; i += 256) {
    int2 e = binned[i];
    int r = atomicAdd(&cnt[e.y - nodeBase], 1);
    csrc[eStart + r] = e.x;
  }
}

// ---------------- dense compute ----------------

// hb[N][64] (bf16) = A[N][KDIM] @ W[KDIM][64]; fused al epilogue from the
// exact fp32 accumulators.
template <int KDIM>
__global__ __launch_bounds__(256) void gemm64(const float* __restrict__ A,
                                              const float* __restrict__ W,
                                              unsigned short* __restrict__ hb,
                                              const float* __restrict__ a_src,
                                              const float* __restrict__ a_dst,
                                              float* __restrict__ alsrc,
                                              float* __restrict__ aldst, int N) {
  __shared__ float As[32][68];
  __shared__ float Ws[32][68];
  const int block_m = blockIdx.x * 64;
  const int t = threadIdx.x;
  const int tc = t & 15;
  const int tr = t >> 4;
  const int c0 = tc * 4, r0 = tr * 4;
  float acc[4][4] = {};

  for (int kc = 0; kc < KDIM; kc += 32) {
    for (int q = t; q < 512; q += 256) {
      int node = q >> 3, f4 = q & 7;
      int gn = block_m + node;
      if (gn >= N) gn = N - 1;
      const float4 v = *(const float4*)(A + (size_t)gn * KDIM + kc + f4 * 4);
      As[f4 * 4 + 0][node] = v.x;
      As[f4 * 4 + 1][node] = v.y;
      As[f4 * 4 + 2][node] = v.z;
      As[f4 * 4 + 3][node] = v.w;
    }
    for (int q = t; q < 512; q += 256) {
      int k = q >> 4, f4 = q & 15;
      const float4 v = *(const float4*)(W + (size_t)(kc + k) * 64 + f4 * 4);
      *(float4*)&Ws[k][f4 * 4] = v;
    }
    __syncthreads();
#pragma unroll
    for (int k = 0; k < 32; ++k) {
      float4 a = *(const float4*)&As[k][r0];
      float4 b = *(const float4*)&Ws[k][c0];
      acc[0][0] += a.x * b.x; acc[0][1] += a.x * b.y; acc[0][2] += a.x * b.z; acc[0][3] += a.x * b.w;
      acc[1][0] += a.y * b.x; acc[1][1] += a.y * b.y; acc[1][2] += a.y * b.z; acc[1][3] += a.y * b.w;
      acc[2][0] += a.z * b.x; acc[2][1] += a.z * b.y; acc[2][2] += a.z * b.z; acc[2][3] += a.z * b.w;
      acc[3][0] += a.w * b.x; acc[3][1] += a.w * b.y; acc[3][2] += a.w * b.z; acc[3][3] += a.w * b.w;
    }
    __syncthreads();
  }

  const float as0 = a_src[c0], as1 = a_src[c0 + 1], as2 = a_src[c0 + 2], as3 = a_src[c0 + 3];
  const float ad0 = a_dst[c0], ad1 = a_dst[c0 + 1], ad2 = a_dst[c0 + 2], ad3 = a_dst[c0 + 3];
#pragma unroll
  for (int i = 0; i < 4; ++i) {
    int gn = block_m + r0 + i;
    if (gn < N) {
      ushort4 u;
      u.x = f2bf(acc[i][0]); u.y = f2bf(acc[i][1]);
      u.z = f2bf(acc[i][2]); u.w = f2bf(acc[i][3]);
      *(ushort4*)(hb + (size_t)gn * 64 + c0) = u;
    }
    float ps = acc[i][0] * as0 + acc[i][1] * as1 + acc[i][2] * as2 + acc[i][3] * as3;
    float pd = acc[i][0] * ad0 + acc[i][1] * ad1 + acc[i][2] * ad2 + acc[i][3] * ad3;
#pragma unroll
    for (int off = 1; off < 16; off <<= 1) {
      ps += __shfl_xor(ps, off, 64);
      pd += __shfl_xor(pd, off, 64);
    }
    if (tc == 0 && gn < N) {
      alsrc[gn] = ps;
      aldst[gn] = pd;
    }
  }
}

// Fused softmax + spmm: one 16-lane group per dst node. Per 16-edge chunk:
// csrc chunk load -> 16-deep row burst issues immediately (depends only on
// csrc); alsrc gather + leaky + group-max + online-softmax rescale runs
// UNDER the row-load latency; FMAs join both. acc/ssum normalization at the
// end (deterministic chunk order). Dense row write, no atomics.
template <int ELU>
__global__ __launch_bounds__(256) void spmm_fused_kernel(
    const int* __restrict__ rowptr, const int* __restrict__ csrc,
    const float* __restrict__ alsrc, const float* __restrict__ aldst,
    const unsigned short* __restrict__ hb, const float* __restrict__ bias,
    float* __restrict__ outbuf, int N) {
  const int t = threadIdx.x;
  const int l = t & 15;   // slot within group
  const int gb = t & 48;  // group base lane within wave
  const int node = blockIdx.x * 16 + (t >> 4);
  if (node >= N) return;
  const int start = rowptr[node];
  const int end = rowptr[node + 1];
  const float ad = aldst[node];

  float m = -1e30f;  // running max
  float ssum = 0.f;  // running sum of exp (relative to m)
  float4 acc0 = make_float4(0.f, 0.f, 0.f, 0.f);
  float4 acc1 = make_float4(0.f, 0.f, 0.f, 0.f);
  float4 acc2 = make_float4(0.f, 0.f, 0.f, 0.f);
  float4 acc3 = make_float4(0.f, 0.f, 0.f, 0.f);

  for (int base = start; base < end; base += 16) {
    int i = base + l;
    bool valid = i < end;
    int s = valid ? csrc[i] : 0;          // coalesced chunk load
    float al = alsrc[s];                  // L2-hot 4B gather (400KB array)

    // issue the 16 row loads FIRST (depend only on csrc shuffles)
    ushort4 u[16];
#pragma unroll
    for (int j = 0; j < 16; ++j) {
      int sj = __shfl(s, gb + j, 64);
      u[j] = *(const ushort4*)(hb + (size_t)sj * 64 + l * 4);
    }

    // softmax chain overlaps the row-load latency
    float e = al + ad;
    e = (e > 0.f) ? e : 0.2f * e;  // leaky_relu 0.2
    if (!valid) e = -1e30f;
    float cmax = e;
#pragma unroll
    for (int off = 1; off < 16; off <<= 1) cmax = fmaxf(cmax, __shfl_xor(cmax, off, 64));
    float newm = fmaxf(m, cmax);
    float scale = __expf(m - newm);  // first chunk: exp(-inf)=0
    float w = valid ? __expf(e - newm) : 0.f;
    float wsum = w;
#pragma unroll
    for (int off = 1; off < 16; off <<= 1) wsum += __shfl_xor(wsum, off, 64);
    ssum = ssum * scale + wsum;
    acc0.x *= scale; acc0.y *= scale; acc0.z *= scale; acc0.w *= scale;
    acc1.x *= scale; acc1.y *= scale; acc1.z *= scale; acc1.w *= scale;
    acc2.x *= scale; acc2.y *= scale; acc2.z *= scale; acc2.w *= scale;
    acc3.x *= scale; acc3.y *= scale; acc3.z *= scale; acc3.w *= scale;
    m = newm;

#pragma unroll
    for (int j = 0; j < 16; ++j) {
      float wj = __shfl(w, gb + j, 64);
      float4* A = ((j & 3) == 0) ? &acc0 : ((j & 3) == 1) ? &acc1
                : ((j & 3) == 2) ? &acc2 : &acc3;
      A->x += wj * bf2f(u[j].x);
      A->y += wj * bf2f(u[j].y);
      A->z += wj * bf2f(u[j].z);
      A->w += wj * bf2f(u[j].w);
    }
  }

  float inv = 1.0f / ssum;  // >= 1 edge (self-loop)
  float4 r;
  r.x = ((acc0.x + acc1.x) + (acc2.x + acc3.x)) * inv;
  r.y = ((acc0.y + acc1.y) + (acc2.y + acc3.y)) * inv;
  r.z = ((acc0.z + acc1.z) + (acc2.z + acc3.z)) * inv;
  r.w = ((acc0.w + acc1.w) + (acc2.w + acc3.w)) * inv;
  if (ELU) {
    const float4 b4 = *(const float4*)(bias + l * 4);
    r.x += b4.x; r.y += b4.y; r.z += b4.z; r.w += b4.w;
    r.x = (r.x > 0.f) ? r.x : expm1f(r.x);
    r.y = (r.y > 0.f) ? r.y : expm1f(r.y);
    r.z = (r.z > 0.f) ? r.z : expm1f(r.z);
    r.w = (r.w > 0.f) ? r.w : expm1f(r.w);
  }
  *(float4*)(outbuf + (size_t)node * 64 + l * 4) = r;
}

// bias + ELU + hierarchical mean-pool accumulation (layer 2) — unchanged.
__global__ __launch_bounds__(256) void post_pool_kernel(
    const float* __restrict__ acc, const float* __restrict__ bias,
    const int* __restrict__ batch, float* __restrict__ pool, int N) {
  __shared__ float4 red4[16][17];
  __shared__ int sB[16];
  __shared__ int uni;
  const int t = threadIdx.x;
  const int ln = t >> 4;
  const int f4 = t & 15;
  const int base = blockIdx.x * 16;
  const int node = base + ln;

  if (t < 16) {
    int nn = base + t;
    sB[t] = (nn < N) ? batch[nn] : -1;
  }
  __syncthreads();
  if (t == 0) {
    int u = (base + 15 < N);
    for (int i = 1; i < 16; i++) u &= (sB[i] == sB[0]);
    uni = u;
  }

  float4 v = make_float4(0.f, 0.f, 0.f, 0.f);
  if (node < N) {
    v = *(const float4*)(acc + ((size_t)node * 16 + f4) * 4);
    const float4 b4 = *(const float4*)(bias + f4 * 4);
    v.x += b4.x; v.y += b4.y; v.z += b4.z; v.w += b4.w;
    v.x = (v.x > 0.f) ? v.x : expm1f(v.x);
    v.y = (v.y > 0.f) ? v.y : expm1f(v.y);
    v.z = (v.z > 0.f) ? v.z : expm1f(v.z);
    v.w = (v.w > 0.f) ? v.w : expm1f(v.w);
  }
  red4[ln][f4] = v;
  __syncthreads();

  if (t < 64) {
    const float* rf = (const float*)red4;  // row stride 68 floats
    if (uni) {
      float s = 0.f;
#pragma unroll
      for (int n = 0; n < 16; n++) s += rf[n * 68 + t];
      atomicAdd(&pool[(size_t)sB[0] * 64 + t], s);
    } else {
      for (int n = 0; n < 16; n++) {
        int g = sB[n];
        if (g >= 0) atomicAdd(&pool[(size_t)g * 64 + t], rf[n * 68 + t]);
      }
    }
  }
}

// out[g] = (pool[g,:]/cnt[g]) . Wfc + bfc ; cnt from sorted-batch bounds.
__global__ void final_kernel(const float* __restrict__ pool, const int* __restrict__ gstart,
                             const float* __restrict__ Wfc, const float* __restrict__ bfc,
                             float* __restrict__ out, int G) {
  int wid = (blockIdx.x * blockDim.x + threadIdx.x) >> 6;
  int lane = threadIdx.x & 63;
  if (wid >= G) return;
  float c = (float)max(gstart[wid + 1] - gstart[wid], 1);
  float v = pool[(size_t)wid * 64 + lane] * (1.0f / c) * Wfc[lane];
  v = wave_reduce_sum(v);
  if (lane == 0) out[wid] = v + bfc[0];
}

// ---------------------------------------------------------------------------

extern "C" void kernel_launch(void* const* d_in, const int* in_sizes, int n_in,
                              void* d_out, int out_size, void* d_ws, size_t ws_size,
                              hipStream_t stream) {
  const float* x     = (const float*)d_in[0];
  const int*   ei    = (const int*)d_in[1];
  const int*   batch = (const int*)d_in[2];
  const float* W1    = (const float*)d_in[3];
  const float* asrc1 = (const float*)d_in[4];
  const float* adst1 = (const float*)d_in[5];
  const float* b1    = (const float*)d_in[6];
  const float* W2    = (const float*)d_in[7];
  const float* asrc2 = (const float*)d_in[8];
  const float* adst2 = (const float*)d_in[9];
  const float* b2    = (const float*)d_in[10];
  const float* Wfc   = (const float*)d_in[11];
  const float* bfc   = (const float*)d_in[12];
  float* out = (float*)d_out;

  const int N = in_sizes[0] / 128;  // 100000
  const int E = in_sizes[1] / 2;    // 1600000
  const int G = 256;
  const int M = E + N;              // edges incl self-loops
  const int NB = (N + BIN_NODES - 1) >> BIN_SHIFT;  // 391 bins

  // workspace carve (256B aligned)
  char* p = (char*)d_ws;
  auto alloc = [&](size_t bytes) {
    char* r = p;
    p += (bytes + 255) & ~size_t(255);
    return r;
  };
  float*          h1e    = (float*)alloc((size_t)N * 64 * 4);
  float*          accbuf = (float*)alloc((size_t)N * 64 * 4);
  unsigned short* hb     = (unsigned short*)alloc((size_t)N * 64 * 2);
  float* alsrc  = (float*)alloc((size_t)N * 4);
  float* aldst  = (float*)alloc((size_t)N * 4);
  int*   rowptr = (int*)alloc((size_t)(N + 1) * 4);
  int*   csrc   = (int*)alloc((size_t)M * 4);
  int2*  binned = (int2*)alloc((size_t)M * 8);
  int*   binCnt = (int*)alloc((size_t)NB * 4);
  int*   binBase = (int*)alloc((size_t)(NB + 1) * 4);
  int*   binCursor = (int*)alloc((size_t)NB * 4);
  float* pool   = (float*)alloc((size_t)G * 64 * 4);
  int*   gstart = (int*)alloc((size_t)(G + 1) * 4);

  // ---- CSR build (binned) + graph bounds ----
  hipMemsetAsync(binCnt, 0, (size_t)NB * 4, stream);
  bin_count_kernel<<<512, 256, NB * 4, stream>>>(ei, E, M, NB, binCnt);
  scan_bounds_kernel<<<3, 256, 0, stream>>>(binCnt, NB, binBase, binCursor,
                                            batch, gstart, N, G);
  bin_place_kernel<<<(M + PLACE_CHUNK - 1) / PLACE_CHUNK, 256, 2 * NB * 4, stream>>>(
      ei, E, M, NB, binCursor, binned);
  csr_finalize_kernel<<<NB, 256, 0, stream>>>(binned, binBase, rowptr, csrc, N, NB, M);

  // ---- layer 1 ----
  gemm64<128><<<(N + 63) / 64, 256, 0, stream>>>(x, W1, hb, asrc1, adst1, alsrc, aldst, N);
  spmm_fused_kernel<1><<<(N + 15) / 16, 256, 0, stream>>>(rowptr, csrc, alsrc, aldst,
                                                          hb, b1, h1e, N);

  // ---- layer 2 ----
  gemm64<64><<<(N + 63) / 64, 256, 0, stream>>>(h1e, W2, hb, asrc2, adst2, alsrc, aldst, N);
  spmm_fused_kernel<0><<<(N + 15) / 16, 256, 0, stream>>>(rowptr, csrc, alsrc, aldst,
                                                          hb, nullptr, accbuf, N);
  hipMemsetAsync(pool, 0, (size_t)G * 64 * 4, stream);
  post_pool_kernel<<<(N + 15) / 16, 256, 0, stream>>>(accbuf, b2, batch, pool, N);

  // ---- readout ----
  final_kernel<<<(G * 64 + 255) / 256, 256, 0, stream>>>(pool, gstart, Wfc, bfc, out, G);
}